// Round 1
// baseline (2133.536 us; speedup 1.0000x reference)
//
#include <hip/hip_runtime.h>
#include <hip/hip_bf16.h>
#include <math.h>

// Problem constants
#define BB 16
#define LL 512
#define HH 256
#define NHEAD 8
#define HDIM 32
#define LP1 513
#define NHHD 256   // NHEAD*HDIM
#define NODES_ELEMS (BB*LL*HH)          // 2097152
#define RELAY_ELEMS (BB*HH)             // 4096

// ---------------------------------------------------------------------------
// init: relay = mean over L of data
__global__ __launch_bounds__(256) void init_relay_kernel(const float* __restrict__ data,
                                                         float* __restrict__ relay) {
  int b = blockIdx.x, t = threadIdx.x;
  float s = 0.f;
  const float* p = data + (size_t)b * LL * HH + t;
  for (int l = 0; l < LL; l++) s += p[(size_t)l * HH];
  relay[b * HH + t] = s * (1.0f / 512.0f);
}

// ---------------------------------------------------------------------------
// generic transpose: out[c*R + r] = in[r*C + c]
__global__ __launch_bounds__(256) void transpose_kernel(const float* __restrict__ in,
                                                        float* __restrict__ out,
                                                        int R, int C) {
  int idx = blockIdx.x * 256 + threadIdx.x;
  if (idx < R * C) {
    int r = idx / C, c = idx % C;
    out[(size_t)c * R + r] = in[idx];
  }
}

// ---------------------------------------------------------------------------
// LayerNorm over H=256, one block per row
__global__ __launch_bounds__(256) void ln_kernel(const float* __restrict__ nodes,
                                                 const float* __restrict__ g,
                                                 const float* __restrict__ bb,
                                                 float* __restrict__ xn) {
  int row = blockIdx.x;
  int t = threadIdx.x;
  int lane = t & 63, w = t >> 6;
  __shared__ float red[4];
  float x = nodes[(size_t)row * HH + t];
  float s = x;
#pragma unroll
  for (int o = 32; o; o >>= 1) s += __shfl_xor(s, o);
  if (lane == 0) red[w] = s;
  __syncthreads();
  float mean = (red[0] + red[1] + red[2] + red[3]) * (1.0f / 256.0f);
  __syncthreads();
  float d = x - mean;
  float v = d * d;
#pragma unroll
  for (int o = 32; o; o >>= 1) v += __shfl_xor(v, o);
  if (lane == 0) red[w] = v;
  __syncthreads();
  float var = (red[0] + red[1] + red[2] + red[3]) * (1.0f / 256.0f);
  float rstd = rsqrtf(var + 1e-5f);
  xn[(size_t)row * HH + t] = d * rstd * g[t] + bb[t];
}

// ---------------------------------------------------------------------------
// tiled fp32 GEMM: C[M,N] = A[M,K] @ Bm[K,N] + bias[N]
// mode 0: plain
// mode 1 (fc epilogue): C = mask[row] ? resid + leaky_relu(acc+bias, .01) : 0
__global__ __launch_bounds__(256) void gemm_kernel(const float* __restrict__ A,
                                                   const float* __restrict__ Bm,
                                                   const float* __restrict__ bias,
                                                   float* __restrict__ C,
                                                   int M, int N, int K, int mode,
                                                   const float* __restrict__ resid,
                                                   const int* __restrict__ mask) {
  __shared__ float As[16][68];
  __shared__ float Bs[16][64];
  int tile_n = blockIdx.x * 64;
  int tile_m = blockIdx.y * 64;
  int t = threadIdx.x;
  int tx = t & 15, ty = t >> 4;
  float acc[4][4] = {};
  for (int k0 = 0; k0 < K; k0 += 16) {
#pragma unroll
    for (int u = 0; u < 4; u++) {
      int idx = t + u * 256;
      int m = idx >> 4, kk = idx & 15;
      int gm = tile_m + m;
      As[kk][m] = (gm < M) ? A[(size_t)gm * K + k0 + kk] : 0.f;
    }
#pragma unroll
    for (int u = 0; u < 4; u++) {
      int idx = t + u * 256;
      int kk = idx >> 6, n = idx & 63;
      int gn = tile_n + n;
      Bs[kk][n] = (gn < N) ? Bm[(size_t)(k0 + kk) * N + gn] : 0.f;
    }
    __syncthreads();
#pragma unroll
    for (int kk = 0; kk < 16; kk++) {
      float a[4], b[4];
#pragma unroll
      for (int i = 0; i < 4; i++) a[i] = As[kk][ty * 4 + i];
#pragma unroll
      for (int j = 0; j < 4; j++) b[j] = Bs[kk][tx * 4 + j];
#pragma unroll
      for (int i = 0; i < 4; i++)
#pragma unroll
        for (int j = 0; j < 4; j++) acc[i][j] = fmaf(a[i], b[j], acc[i][j]);
    }
    __syncthreads();
  }
#pragma unroll
  for (int i = 0; i < 4; i++) {
    int gm = tile_m + ty * 4 + i;
    if (gm >= M) continue;
#pragma unroll
    for (int j = 0; j < 4; j++) {
      int gn = tile_n + tx * 4 + j;
      if (gn >= N) continue;
      float v = acc[i][j] + bias[gn];
      if (mode == 1) {
        v = v > 0.f ? v : 0.01f * v;
        v = (mask[gm] != 0) ? resid[(size_t)gm * N + gn] + v : 0.f;
      }
      C[(size_t)gm * N + gn] = v;
    }
  }
}

// ---------------------------------------------------------------------------
// per-(head,batch) relay-derived constants:
// ra1[n,b] = sum_k relay[b,k]*a1[n,256+2k+1]; ra2 likewise;
// rf[n,b,d] = sum_k relay[b,k]*Fw[n,256+2k+1,d]
__global__ __launch_bounds__(256) void rarf_kernel(const float* __restrict__ relay,
                                                   const float* __restrict__ a1,
                                                   const float* __restrict__ a2,
                                                   const float* __restrict__ fcw,
                                                   float* __restrict__ ra1,
                                                   float* __restrict__ ra2,
                                                   float* __restrict__ rf) {
  int n = blockIdx.x >> 4, b = blockIdx.x & 15;
  int t = threadIdx.x;
  int lane = t & 63, w = t >> 6;
  __shared__ float rel[256];
  __shared__ float red1[4], red2[4];
  __shared__ float pf_s[8][33];
  rel[t] = relay[b * HH + t];
  __syncthreads();
  float p1 = rel[t] * a1[n * 768 + 257 + 2 * t];
  float p2 = rel[t] * a2[n * 768 + 257 + 2 * t];
#pragma unroll
  for (int o = 32; o; o >>= 1) { p1 += __shfl_xor(p1, o); p2 += __shfl_xor(p2, o); }
  if (lane == 0) { red1[w] = p1; red2[w] = p2; }
  int d = t & 31, seg = t >> 5;
  float pf = 0.f;
  for (int u = 0; u < 32; u++) {
    int k = seg * 32 + u;
    pf = fmaf(rel[k], fcw[((size_t)n * 768 + 257 + 2 * k) * 32 + d], pf);
  }
  pf_s[seg][d] = pf;
  __syncthreads();
  if (t == 0) {
    ra1[n * 16 + b] = red1[0] + red1[1] + red1[2] + red1[3];
    ra2[n * 16 + b] = red2[0] + red2[1] + red2[2] + red2[3];
  }
  if (t < 32) {
    float s = 0.f;
    for (int gg = 0; gg < 8; gg++) s += pf_s[gg][t];
    rf[((size_t)n * 16 + b) * 32 + t] = s;
  }
}

// ---------------------------------------------------------------------------
// ei/ej: one wave per (n,b,l)
__global__ __launch_bounds__(64) void eiej_kernel(const float* __restrict__ qx,
                                                  const float* __restrict__ data,
                                                  const float* __restrict__ a1,
                                                  const float* __restrict__ a2,
                                                  const float* __restrict__ ra1,
                                                  const float* __restrict__ ra2,
                                                  float* __restrict__ ei,
                                                  float* __restrict__ ej) {
  int id = blockIdx.x;           // n*8192 + b*512 + l
  int n = id >> 13;
  int r = id & 8191;             // b*512 + l
  int b = r >> 9;
  int lane = threadIdx.x;
  const float* qrow = qx + (size_t)r * 2048 + n * 256;
  const float* drow = data + (size_t)r * 256;
  float s1 = 0.f, s2 = 0.f;
#pragma unroll
  for (int u = 0; u < 4; u++) {
    int c = lane + u * 64;
    float q = qrow[c], dv = drow[c];
    s1 = fmaf(q, a1[n * 768 + c], s1);
    s1 = fmaf(dv, a1[n * 768 + 256 + 2 * c], s1);
    s2 = fmaf(q, a2[n * 768 + c], s2);
    s2 = fmaf(dv, a2[n * 768 + 256 + 2 * c], s2);
  }
#pragma unroll
  for (int o = 32; o; o >>= 1) { s1 += __shfl_xor(s1, o); s2 += __shfl_xor(s2, o); }
  if (lane == 0) {
    ei[id] = s1 + ra1[n * 16 + b];
    ej[id] = s2 + ra2[n * 16 + b];
  }
}

// ---------------------------------------------------------------------------
// GAT attention + aggregate + output proj: one wave per (n, b, 8 rows)
__global__ __launch_bounds__(64) void gat_attn_kernel(const float* __restrict__ qx,
                                                      const float* __restrict__ data,
                                                      const float* __restrict__ ei,
                                                      const float* __restrict__ ej,
                                                      const int* __restrict__ edge,
                                                      const float* __restrict__ fcw,
                                                      const float* __restrict__ fcb,
                                                      const float* __restrict__ rf,
                                                      float* __restrict__ temp) {
  __shared__ float w_lds[8][512];
  __shared__ float denom_s[8];
  int blk = blockIdx.x;
  int n = blk >> 10;             // 1024 blocks per head (16 b * 64 row-tiles)
  int rem = blk & 1023;
  int b = rem >> 6;
  int i0 = (rem & 63) << 3;
  int lane = threadIdx.x;

  const float* ejrow = ej + (size_t)n * 8192 + b * 512;
  float ejv[8];
#pragma unroll
  for (int u = 0; u < 8; u++) ejv[u] = ejrow[lane + 64 * u];

  // Phase A: softmax weights (unnormalized) for 8 rows
  for (int r = 0; r < 8; r++) {
    int i = i0 + r;
    float eiv = ei[(size_t)n * 8192 + b * 512 + i];
    const int* adj = edge + ((size_t)b * 512 + i) * 512;
    float ev[8];
    float m = -3.0e38f;
#pragma unroll
    for (int u = 0; u < 8; u++) {
      int j = lane + 64 * u;
      float e;
      if (adj[j] > 0) { e = eiv + ejv[u]; e = e > 0.f ? e : 0.2f * e; }
      else e = -9.0e15f;
      ev[u] = e;
      m = fmaxf(m, e);
    }
#pragma unroll
    for (int o = 32; o; o >>= 1) m = fmaxf(m, __shfl_xor(m, o));
    float ssum = 0.f;
#pragma unroll
    for (int u = 0; u < 8; u++) {
      float wv = __expf(ev[u] - m);
      w_lds[r][lane + 64 * u] = wv;
      ssum += wv;
    }
#pragma unroll
    for (int o = 32; o; o >>= 1) ssum += __shfl_xor(ssum, o);
    if (lane == 0) denom_s[r] = ssum;
  }
  __syncthreads();

  // Phase B: aggregate hp = sum_j w_j * [qx_j(256) ; data_j(256)]
  float accq[8][4] = {};
  float accd[8][4] = {};
  const float* qbase = qx + (size_t)b * 512 * 2048 + n * 256 + lane * 4;
  const float* dbase = data + (size_t)b * 512 * 256 + lane * 4;
  for (int j = 0; j < 512; j++) {
    float4 vq = *(const float4*)(qbase + (size_t)j * 2048);
    float4 vd = *(const float4*)(dbase + (size_t)j * 256);
#pragma unroll
    for (int r = 0; r < 8; r++) {
      float wv = w_lds[r][j];
      accq[r][0] = fmaf(wv, vq.x, accq[r][0]);
      accq[r][1] = fmaf(wv, vq.y, accq[r][1]);
      accq[r][2] = fmaf(wv, vq.z, accq[r][2]);
      accq[r][3] = fmaf(wv, vq.w, accq[r][3]);
      accd[r][0] = fmaf(wv, vd.x, accd[r][0]);
      accd[r][1] = fmaf(wv, vd.y, accd[r][1]);
      accd[r][2] = fmaf(wv, vd.z, accd[r][2]);
      accd[r][3] = fmaf(wv, vd.w, accd[r][3]);
    }
  }
  __syncthreads();

  // normalize and park hp in LDS (reuse w_lds)
#pragma unroll
  for (int r = 0; r < 8; r++) {
    float inv = 1.0f / denom_s[r];
    *(float4*)&w_lds[r][lane * 4] =
        make_float4(accq[r][0] * inv, accq[r][1] * inv, accq[r][2] * inv, accq[r][3] * inv);
    *(float4*)&w_lds[r][256 + lane * 4] =
        make_float4(accd[r][0] * inv, accd[r][1] * inv, accd[r][2] * inv, accd[r][3] * inv);
  }
  __syncthreads();

  // Phase C: out[d] = elu( hp . Fw + rf + Fb )
  int d = lane & 31, half = lane >> 5;
  const float* fw = fcw + (size_t)n * 768 * 32;
  int ldsBase = half * 256;
  int fwBase = half * 256;
  int fwMul = 1 + half;
  for (int r = 0; r < 8; r++) {
    float acc = 0.f;
    for (int c = 0; c < 256; c++)
      acc = fmaf(w_lds[r][ldsBase + c], fw[(size_t)(fwBase + fwMul * c) * 32 + d], acc);
    acc += __shfl_down(acc, 32);
    if (half == 0) {
      float v = acc + fcb[n * 32 + d] + rf[((size_t)n * 16 + b) * 32 + d];
      v = v > 0.f ? v : expm1f(v);
      temp[((size_t)b * 512 + i0 + r) * 256 + n * 32 + d] = v;
    }
  }
}

// ---------------------------------------------------------------------------
// y = concat([relay, nodes], dim=1) rows
__global__ __launch_bounds__(256) void build_y_kernel(const float* __restrict__ relay,
                                                      const float* __restrict__ nodes,
                                                      float* __restrict__ y) {
  int row = blockIdx.x;          // b*513 + l
  int b = row / LP1, l = row % LP1;
  const float* src = (l == 0) ? relay + (size_t)b * HH
                              : nodes + ((size_t)b * LL + l - 1) * HH;
  y[(size_t)row * HH + threadIdx.x] = src[threadIdx.x];
}

// ---------------------------------------------------------------------------
// small row GEMM (M tiny): out[row,c] = act( in[row,:] . WT[:,c] + bias[c] )
__global__ __launch_bounds__(256) void small_gemm_kernel(const float* __restrict__ in,
                                                         const float* __restrict__ WT,
                                                         const float* __restrict__ bias,
                                                         float* __restrict__ out,
                                                         int act) {
  int row = blockIdx.x;
  int t = threadIdx.x;
  __shared__ float xr[256];
  xr[t] = in[(size_t)row * 256 + t];
  __syncthreads();
  float acc = 0.f;
  for (int k = 0; k < 256; k++) acc = fmaf(xr[k], WT[(size_t)k * 256 + t], acc);
  float v = acc + bias[t];
  if (act == 1) v = v > 0.f ? v : 0.01f * v;
  out[(size_t)row * 256 + t] = v;
}

// ---------------------------------------------------------------------------
// star attention: one block per (b, n)
__global__ __launch_bounds__(256) void star_attn_kernel(const float* __restrict__ qstar,
                                                        const float* __restrict__ kt,
                                                        const int* __restrict__ mask,
                                                        float* __restrict__ attstar) {
  int b = blockIdx.x >> 3, n = blockIdx.x & 7;
  int t = threadIdx.x;
  int lane = t & 63, w = t >> 6;
  __shared__ float qv[32];
  __shared__ float pre[LP1];
  __shared__ float red[4];
  __shared__ float par[8][33];
  if (t < 32) qv[t] = qstar[b * 256 + n * 32 + t];
  __syncthreads();
  const float scale = 0.17677669529663687f;  // 1/sqrt(32)
  for (int l = t; l < LP1; l += 256) {
    bool masked = (l > 0) && (mask[b * LL + l - 1] == 0);
    float p;
    if (masked) p = -3.4e38f;
    else {
      p = 0.f;
      const float* krow = kt + ((size_t)b * LP1 + l) * 256 + n * 32;
      for (int d = 0; d < 32; d++) p = fmaf(qv[d], krow[d], p);
      p *= scale;
    }
    pre[l] = p;
  }
  __syncthreads();
  float m = -3.4e38f;
  for (int l = t; l < LP1; l += 256) m = fmaxf(m, pre[l]);
#pragma unroll
  for (int o = 32; o; o >>= 1) m = fmaxf(m, __shfl_xor(m, o));
  if (lane == 0) red[w] = m;
  __syncthreads();
  m = fmaxf(fmaxf(red[0], red[1]), fmaxf(red[2], red[3]));
  __syncthreads();
  float s = 0.f;
  for (int l = t; l < LP1; l += 256) {
    float wv = __expf(pre[l] - m);
    pre[l] = wv;
    s += wv;
  }
#pragma unroll
  for (int o = 32; o; o >>= 1) s += __shfl_xor(s, o);
  if (lane == 0) red[w] = s;
  __syncthreads();
  float denom = red[0] + red[1] + red[2] + red[3];
  int d = t & 31, g = t >> 5;
  float acc = 0.f;
  for (int l = g; l < LP1; l += 8)
    acc = fmaf(pre[l], kt[((size_t)b * LP1 + l) * 256 + n * 32 + d], acc);
  par[g][d] = acc;
  __syncthreads();
  if (t < 32) {
    float a = 0.f;
    for (int gg = 0; gg < 8; gg++) a += par[gg][t];
    attstar[b * 256 + n * 32 + t] = a / denom;
  }
}

// ---------------------------------------------------------------------------
extern "C" void kernel_launch(void* const* d_in, const int* in_sizes, int n_in,
                              void* d_out, int out_size, void* d_ws, size_t ws_size,
                              hipStream_t stream) {
  const float* data  = (const float*)d_in[0];
  const float* WQw   = (const float*)d_in[1];
  const float* WQb   = (const float*)d_in[2];
  const float* a1    = (const float*)d_in[3];
  const float* a2    = (const float*)d_in[4];
  const float* fcw_g = (const float*)d_in[5];
  const float* fcb_g = (const float*)d_in[6];
  const float* ng    = (const float*)d_in[7];
  const float* nb    = (const float*)d_in[8];
  const float* sq_w  = (const float*)d_in[9];
  const float* sq_b  = (const float*)d_in[10];
  const float* sk_w  = (const float*)d_in[11];
  const float* sk_b  = (const float*)d_in[12];
  const float* so_w  = (const float*)d_in[13];
  const float* so_b  = (const float*)d_in[14];
  const float* fc_w  = (const float*)d_in[15];
  const float* fc_b  = (const float*)d_in[16];
  const int*   mask  = (const int*)d_in[17];
  const int*   edge  = (const int*)d_in[18];

  float* nodes = (float*)d_out;                 // [B,L,H]
  float* relay = nodes + NODES_ELEMS;           // [B,H]

  float* ws = (float*)d_ws;
  size_t o = 0;
  float* xn   = ws + o; o += (size_t)BB * LL * HH;        // 2097152
  float* qx   = ws + o; o += (size_t)BB * LL * NHEAD * HH; // 16777216
  float* ei   = ws + o; o += (size_t)NHEAD * BB * LL;      // 65536
  float* ej   = ws + o; o += (size_t)NHEAD * BB * LL;      // 65536
  float* ra1  = ws + o; o += NHEAD * BB;                   // 128
  float* ra2  = ws + o; o += NHEAD * BB;                   // 128
  float* rf   = ws + o; o += NHEAD * BB * HDIM;            // 4096
  float* temp = ws + o; o += (size_t)BB * LL * NHHD;       // 2097152
  float* y    = ws + o; o += (size_t)BB * LP1 * HH;        // 2101248
  float* kt   = ws + o; o += (size_t)BB * LP1 * NHHD;      // 2101248
  float* qst  = ws + o; o += BB * NHHD;                    // 4096
  float* atts = ws + o; o += BB * NHHD;                    // 4096
  float* wqT  = ws + o; o += (size_t)HH * NHEAD * HH;      // 524288
  float* sqT  = ws + o; o += 2 * 65536;
  float* skT  = ws + o; o += 2 * 65536;
  float* soT  = ws + o; o += 2 * 65536;

  // nodes = data; relay = mean_L(data)
  hipMemcpyAsync(nodes, data, (size_t)NODES_ELEMS * sizeof(float),
                 hipMemcpyDeviceToDevice, stream);
  init_relay_kernel<<<BB, 256, 0, stream>>>(data, relay);

  // weight transposes (done every call; cheap)
  transpose_kernel<<<(2048 * 256 + 255) / 256, 256, 0, stream>>>(WQw, wqT, 2048, 256);
  for (int it = 0; it < 2; it++) {
    transpose_kernel<<<256, 256, 0, stream>>>(sq_w + it * 65536, sqT + it * 65536, 256, 256);
    transpose_kernel<<<256, 256, 0, stream>>>(sk_w + it * 65536, skT + it * 65536, 256, 256);
    transpose_kernel<<<256, 256, 0, stream>>>(so_w + it * 65536, soT + it * 65536, 256, 256);
  }

  for (int it = 0; it < 2; it++) {
    ln_kernel<<<BB * LL, 256, 0, stream>>>(nodes, ng + it * 256, nb + it * 256, xn);
    // qx[b*l, n*256+c] = xn @ WqT (all heads as one GEMM)
    gemm_kernel<<<dim3(32, 128), 256, 0, stream>>>(xn, wqT, WQb, qx,
                                                   8192, 2048, 256, 0, nullptr, nullptr);
    rarf_kernel<<<NHEAD * BB, 256, 0, stream>>>(relay, a1, a2, fcw_g, ra1, ra2, rf);
    eiej_kernel<<<NHEAD * BB * LL, 64, 0, stream>>>(qx, data, a1, a2, ra1, ra2, ei, ej);
    gat_attn_kernel<<<NHEAD * BB * (LL / 8), 64, 0, stream>>>(qx, data, ei, ej, edge,
                                                              fcw_g, fcb_g, rf, temp);
    // nodes = mask ? nodes + lrelu(temp @ fc_w + fc_b) : 0
    gemm_kernel<<<dim3(4, 128), 256, 0, stream>>>(temp, fc_w, fc_b, nodes,
                                                  8192, 256, 256, 1, nodes, mask);
    build_y_kernel<<<BB * LP1, 256, 0, stream>>>(relay, nodes, y);
    gemm_kernel<<<dim3(4, 129), 256, 0, stream>>>(y, skT + it * 65536, sk_b + it * 256,
                                                  kt, BB * LP1, 256, 256, 0, nullptr, nullptr);
    small_gemm_kernel<<<BB, 256, 0, stream>>>(relay, sqT + it * 65536, sq_b + it * 256,
                                              qst, 0);
    star_attn_kernel<<<BB * NHEAD, 256, 0, stream>>>(qst, kt, mask, atts);
    small_gemm_kernel<<<BB, 256, 0, stream>>>(atts, soT + it * 65536, so_b + it * 256,
                                              relay, 1);
  }
}

// Round 2
// 860.541 us; speedup vs baseline: 2.4793x; 2.4793x over previous
//
#include <hip/hip_runtime.h>
#include <hip/hip_bf16.h>
#include <math.h>

#define BB 16
#define LL 512
#define HH 256
#define NHEAD 8
#define HDIM 32
#define LP1 513
#define NHHD 256
#define NODES_ELEMS (BB*LL*HH)

typedef __attribute__((ext_vector_type(8))) short bf16x8;
typedef __attribute__((ext_vector_type(4))) float f32x4;

__device__ __forceinline__ unsigned short f2bf(float f) {
  union { float f; unsigned u; } x; x.f = f;
  unsigned r = x.u + 0x7fffu + ((x.u >> 16) & 1u);
  return (unsigned short)(r >> 16);
}

// ---------------------------------------------------------------------------
__global__ __launch_bounds__(256) void init_relay_kernel(const float* __restrict__ data,
                                                         float* __restrict__ relay) {
  int b = blockIdx.x, t = threadIdx.x;
  float s = 0.f;
  const float* p = data + (size_t)b * LL * HH + t;
  for (int l = 0; l < LL; l++) s += p[(size_t)l * HH];
  relay[b * HH + t] = s * (1.0f / 512.0f);
}

// generic fp32 transpose out[c*R+r] = in[r*C+c]
__global__ __launch_bounds__(256) void transpose_kernel(const float* __restrict__ in,
                                                        float* __restrict__ out,
                                                        int R, int C) {
  int idx = blockIdx.x * 256 + threadIdx.x;
  if (idx < R * C) {
    int r = idx / C, c = idx % C;
    out[(size_t)c * R + r] = in[idx];
  }
}

// elementwise fp32 -> bf16
__global__ __launch_bounds__(256) void cvt_bf16_kernel(const float* __restrict__ in,
                                                       unsigned short* __restrict__ out,
                                                       int n) {
  int idx = blockIdx.x * 256 + threadIdx.x;
  if (idx < n) out[idx] = f2bf(in[idx]);
}

// fc_w [256 k][256 o] -> fcwT[o][k] bf16
__global__ __launch_bounds__(256) void fcwT_kernel(const float* __restrict__ in,
                                                   unsigned short* __restrict__ out) {
  int idx = blockIdx.x * 256 + threadIdx.x;   // idx = o*256 + k
  int o = idx >> 8, k = idx & 255;
  out[idx] = f2bf(in[k * 256 + o]);
}

// fw2T[n][d][c] = Fw[n][c<256 ? c : 2c-256][d] bf16
__global__ __launch_bounds__(256) void fw2T_kernel(const float* __restrict__ fcw,
                                                   unsigned short* __restrict__ out) {
  int idx = blockIdx.x * 256 + threadIdx.x;   // ((n*32+d)*512)+c
  int c = idx & 511, d = (idx >> 9) & 31, n = idx >> 14;
  int srow = (c < 256) ? c : (2 * c - 256);
  out[idx] = f2bf(fcw[((size_t)n * 768 + srow) * 32 + d]);
}

// dataT[b][c][j] bf16 from data[b][j][c], LDS-tiled
__global__ void dataT_kernel(const float* __restrict__ data,
                             unsigned short* __restrict__ dataT) {
  __shared__ float tile[32][33];
  int b = blockIdx.z, j0 = blockIdx.x * 32, c0 = blockIdx.y * 32;
  tile[threadIdx.y][threadIdx.x] =
      data[((size_t)(b * 512 + j0 + threadIdx.y)) * 256 + c0 + threadIdx.x];
  __syncthreads();
  dataT[((size_t)(b * 256 + c0 + threadIdx.y)) * 512 + j0 + threadIdx.x] =
      f2bf(tile[threadIdx.x][threadIdx.y]);
}

// w1[n][k] = sum_c a1[n][c]*WQw[n][c][k]; c1[n] = sum_c a1[n][c]*WQb[n][c]
__global__ __launch_bounds__(256) void w12_kernel(const float* __restrict__ WQw,
                                                  const float* __restrict__ WQb,
                                                  const float* __restrict__ a1,
                                                  const float* __restrict__ a2,
                                                  float* __restrict__ w1,
                                                  float* __restrict__ w2,
                                                  float* __restrict__ c1,
                                                  float* __restrict__ c2) {
  int n = blockIdx.x, t = threadIdx.x;
  float s1 = 0.f, s2 = 0.f;
  for (int c = 0; c < 256; c++) {
    float wv = WQw[((size_t)(n * 256 + c)) * 256 + t];
    s1 = fmaf(a1[n * 768 + c], wv, s1);
    s2 = fmaf(a2[n * 768 + c], wv, s2);
  }
  w1[n * 256 + t] = s1;
  w2[n * 256 + t] = s2;
  __shared__ float r1[256], r2[256];
  r1[t] = a1[n * 768 + t] * WQb[n * 256 + t];
  r2[t] = a2[n * 768 + t] * WQb[n * 256 + t];
  __syncthreads();
  for (int o = 128; o; o >>= 1) {
    if (t < o) { r1[t] += r1[t + o]; r2[t] += r2[t + o]; }
    __syncthreads();
  }
  if (t == 0) { c1[n] = r1[0]; c2[n] = r2[0]; }
}

// ---------------------------------------------------------------------------
// LayerNorm, also emits bf16 copy
__global__ __launch_bounds__(256) void ln_kernel(const float* __restrict__ nodes,
                                                 const float* __restrict__ g,
                                                 const float* __restrict__ bb,
                                                 float* __restrict__ xn,
                                                 unsigned short* __restrict__ xnb) {
  int row = blockIdx.x;
  int t = threadIdx.x;
  int lane = t & 63, w = t >> 6;
  __shared__ float red[4];
  float x = nodes[(size_t)row * HH + t];
  float s = x;
#pragma unroll
  for (int o = 32; o; o >>= 1) s += __shfl_xor(s, o);
  if (lane == 0) red[w] = s;
  __syncthreads();
  float mean = (red[0] + red[1] + red[2] + red[3]) * (1.0f / 256.0f);
  __syncthreads();
  float d = x - mean;
  float v = d * d;
#pragma unroll
  for (int o = 32; o; o >>= 1) v += __shfl_xor(v, o);
  if (lane == 0) red[w] = v;
  __syncthreads();
  float var = (red[0] + red[1] + red[2] + red[3]) * (1.0f / 256.0f);
  float rstd = rsqrtf(var + 1e-5f);
  float out = d * rstd * g[t] + bb[t];
  xn[(size_t)row * HH + t] = out;
  xnb[(size_t)row * HH + t] = f2bf(out);
}

// relay-derived constants (fp32)
__global__ __launch_bounds__(256) void rarf_kernel(const float* __restrict__ relay,
                                                   const float* __restrict__ a1,
                                                   const float* __restrict__ a2,
                                                   const float* __restrict__ fcw,
                                                   float* __restrict__ ra1,
                                                   float* __restrict__ ra2,
                                                   float* __restrict__ rf) {
  int n = blockIdx.x >> 4, b = blockIdx.x & 15;
  int t = threadIdx.x;
  int lane = t & 63, w = t >> 6;
  __shared__ float rel[256];
  __shared__ float red1[4], red2[4];
  __shared__ float pf_s[8][33];
  rel[t] = relay[b * HH + t];
  __syncthreads();
  float p1 = rel[t] * a1[n * 768 + 257 + 2 * t];
  float p2 = rel[t] * a2[n * 768 + 257 + 2 * t];
#pragma unroll
  for (int o = 32; o; o >>= 1) { p1 += __shfl_xor(p1, o); p2 += __shfl_xor(p2, o); }
  if (lane == 0) { red1[w] = p1; red2[w] = p2; }
  int d = t & 31, seg = t >> 5;
  float pf = 0.f;
  for (int u = 0; u < 32; u++) {
    int k = seg * 32 + u;
    pf = fmaf(rel[k], fcw[((size_t)n * 768 + 257 + 2 * k) * 32 + d], pf);
  }
  pf_s[seg][d] = pf;
  __syncthreads();
  if (t == 0) {
    ra1[n * 16 + b] = red1[0] + red1[1] + red1[2] + red1[3];
    ra2[n * 16 + b] = red2[0] + red2[1] + red2[2] + red2[3];
  }
  if (t < 32) {
    float s = 0.f;
    for (int gg = 0; gg < 8; gg++) s += pf_s[gg][t];
    rf[((size_t)n * 16 + b) * 32 + t] = s;
  }
}

// ei/ej from xn/data via folded weights
__global__ __launch_bounds__(64) void eiej2_kernel(const float* __restrict__ xn,
                                                   const float* __restrict__ data,
                                                   const float* __restrict__ w1,
                                                   const float* __restrict__ w2,
                                                   const float* __restrict__ a1,
                                                   const float* __restrict__ a2,
                                                   const float* __restrict__ c1,
                                                   const float* __restrict__ c2,
                                                   const float* __restrict__ ra1,
                                                   const float* __restrict__ ra2,
                                                   float* __restrict__ ei,
                                                   float* __restrict__ ej) {
  int id = blockIdx.x;           // n*8192 + b*512 + l
  int n = id >> 13;
  int r = id & 8191;
  int b = r >> 9;
  int lane = threadIdx.x;
  const float* xr = xn + (size_t)r * 256;
  const float* dr = data + (size_t)r * 256;
  float s1 = 0.f, s2 = 0.f;
#pragma unroll
  for (int u = 0; u < 4; u++) {
    int c = lane + 64 * u;
    float xv = xr[c], dv = dr[c];
    s1 = fmaf(xv, w1[n * 256 + c], s1);
    s1 = fmaf(dv, a1[n * 768 + 256 + 2 * c], s1);
    s2 = fmaf(xv, w2[n * 256 + c], s2);
    s2 = fmaf(dv, a2[n * 768 + 256 + 2 * c], s2);
  }
#pragma unroll
  for (int o = 32; o; o >>= 1) { s1 += __shfl_xor(s1, o); s2 += __shfl_xor(s2, o); }
  if (lane == 0) {
    ei[id] = s1 + c1[n] + ra1[n * 16 + b];
    ej[id] = s2 + c2[n] + ra2[n * 16 + b];
  }
}

// ---------------------------------------------------------------------------
// MFMA GEMM over K=256 bf16: C[M,N] = A @ B(+bias)
// A [M][256] bf16 row-major; Bw [N][256] bf16 (per-col contiguous K)
// mode 0: out = qxT bf16 transposed-per-head; mode 1: fc epilogue fp32;
// mode 2: plain fp32 (kt)
__global__ __launch_bounds__(256) void mfma_gemm_kernel(
    const unsigned short* __restrict__ A, const unsigned short* __restrict__ Bw,
    const float* __restrict__ bias, int Mvalid, int mode,
    float* __restrict__ outF, unsigned short* __restrict__ outT,
    const float* __restrict__ resid, const int* __restrict__ mask) {
  int tileN = blockIdx.x * 64;
  int tileM = blockIdx.y * 64;
  int t = threadIdx.x;
  int wv = t >> 6, lane = t & 63;
  int lo = lane & 15, quad = lane >> 4;
  int rowBase = tileM + wv * 16;
  int arow = rowBase + lo;
  if (arow >= Mvalid) arow = Mvalid - 1;
  const unsigned short* aptr = A + (size_t)arow * 256 + quad * 8;
  f32x4 acc[4] = {};
  for (int k0 = 0; k0 < 256; k0 += 32) {
    bf16x8 af = *(const bf16x8*)(aptr + k0);
#pragma unroll
    for (int ct = 0; ct < 4; ct++) {
      bf16x8 bf_ = *(const bf16x8*)(Bw + (size_t)(tileN + ct * 16 + lo) * 256 + k0 + quad * 8);
      acc[ct] = __builtin_amdgcn_mfma_f32_16x16x32_bf16(af, bf_, acc[ct], 0, 0, 0);
    }
  }
#pragma unroll
  for (int ct = 0; ct < 4; ct++) {
    int co = tileN + ct * 16 + lo;
    float bv = bias[co];
    if (mode == 0) {
      int jrow = rowBase + quad * 4;
      int bb2 = jrow >> 9, jj = jrow & 511;
      int hn = co >> 8, cc = co & 255;
      ushort4 pk;
      pk.x = f2bf(acc[ct][0] + bv);
      pk.y = f2bf(acc[ct][1] + bv);
      pk.z = f2bf(acc[ct][2] + bv);
      pk.w = f2bf(acc[ct][3] + bv);
      *(ushort4*)&outT[(((size_t)(hn * 16 + bb2) * 256 + cc) << 9) + jj] = pk;
    } else {
#pragma unroll
      for (int r = 0; r < 4; r++) {
        int row = rowBase + quad * 4 + r;
        if (row >= Mvalid) continue;
        float v = acc[ct][r] + bv;
        if (mode == 1) {
          v = v > 0.f ? v : 0.01f * v;
          v = (mask[row] != 0) ? resid[(size_t)row * 256 + co] + v : 0.f;
        }
        outF[(size_t)row * 256 + co] = v;
      }
    }
  }
}

// ---------------------------------------------------------------------------
// GAT: softmax (fp32) -> MFMA aggregation -> MFMA output proj
// block: (n, b, 32 rows), 256 threads / 4 waves
__global__ __launch_bounds__(256) void gat_mfma_kernel(
    const unsigned short* __restrict__ qxT,   // [8][16][256][512] bf16
    const unsigned short* __restrict__ dataT, // [16][256][512] bf16
    const float* __restrict__ ei, const float* __restrict__ ej,
    const int* __restrict__ edge,
    const unsigned short* __restrict__ fw2T,  // [8][32][512] bf16
    const float* __restrict__ fcb, const float* __restrict__ rf,
    unsigned short* __restrict__ tempb) {     // [8192][256] bf16
  __shared__ unsigned short W[32][520];       // weights, then hp (stride 520: 16B-aligned rows)
  int blk = blockIdx.x;
  int n = blk >> 8;
  int b = (blk >> 4) & 15;
  int i0 = (blk & 15) << 5;
  int t = threadIdx.x;
  int wv = t >> 6, lane = t & 63;
  int lo = lane & 15, quad = lane >> 4;

  // ---- Phase A: per-row softmax over 512 neighbors, normalized bf16 -> LDS
  const float* ejrow = ej + n * 8192 + b * 512;
  float ejv[8];
#pragma unroll
  for (int u = 0; u < 8; u++) ejv[u] = ejrow[lane + 64 * u];
  for (int rr = 0; rr < 8; rr++) {
    int row = wv * 8 + rr;
    float eiv = ei[n * 8192 + b * 512 + i0 + row];
    const int* adj = edge + (((size_t)b * 512 + i0 + row) << 9);
    float evv[8];
    float m = -3.0e38f;
#pragma unroll
    for (int u = 0; u < 8; u++) {
      int j = lane + 64 * u;
      float e;
      if (adj[j] > 0) { e = eiv + ejv[u]; e = e > 0.f ? e : 0.2f * e; }
      else e = -9.0e15f;
      evv[u] = e;
      m = fmaxf(m, e);
    }
#pragma unroll
    for (int o = 32; o; o >>= 1) m = fmaxf(m, __shfl_xor(m, o));
    float s = 0.f;
#pragma unroll
    for (int u = 0; u < 8; u++) {
      float wexp = __expf(evv[u] - m);
      evv[u] = wexp;
      s += wexp;
    }
#pragma unroll
    for (int o = 32; o; o >>= 1) s += __shfl_xor(s, o);
    float inv = 1.0f / s;
#pragma unroll
    for (int u = 0; u < 8; u++) W[row][lane + 64 * u] = f2bf(evv[u] * inv);
  }
  __syncthreads();

  // ---- Phase B: hp[32 rows, 512 cols] = W @ H ; wave wv owns cols wv*128..+127
  const unsigned short* hbase =
      (wv < 2) ? qxT + (((size_t)(n * 16 + b)) * 256 + wv * 128) * 512
               : dataT + (((size_t)b) * 256 + (wv - 2) * 128) * 512;
  f32x4 acc[2][8] = {};
  for (int j0 = 0; j0 < 512; j0 += 32) {
    bf16x8 af0 = *(const bf16x8*)&W[lo][j0 + quad * 8];
    bf16x8 af1 = *(const bf16x8*)&W[16 + lo][j0 + quad * 8];
#pragma unroll
    for (int ct = 0; ct < 8; ct++) {
      bf16x8 bf_ = *(const bf16x8*)(hbase + ((size_t)(ct * 16 + lo)) * 512 + j0 + quad * 8);
      acc[0][ct] = __builtin_amdgcn_mfma_f32_16x16x32_bf16(af0, bf_, acc[0][ct], 0, 0, 0);
      acc[1][ct] = __builtin_amdgcn_mfma_f32_16x16x32_bf16(af1, bf_, acc[1][ct], 0, 0, 0);
    }
  }
  __syncthreads();   // done reading W

  // park hp (bf16) in LDS, layout [row][c]
#pragma unroll
  for (int rt = 0; rt < 2; rt++)
#pragma unroll
    for (int ct = 0; ct < 8; ct++) {
      int c = wv * 128 + ct * 16 + lo;
#pragma unroll
      for (int r = 0; r < 4; r++)
        W[rt * 16 + quad * 4 + r][c] = f2bf(acc[rt][ct][r]);
    }
  __syncthreads();

  // ---- Phase C: out[32 rows, 32 d] = hp @ fw2 (waves redundant; wave 0 stores)
  f32x4 acc2[2][2] = {};
  for (int k0 = 0; k0 < 512; k0 += 32) {
    bf16x8 a0 = *(const bf16x8*)&W[lo][k0 + quad * 8];
    bf16x8 a1f = *(const bf16x8*)&W[16 + lo][k0 + quad * 8];
#pragma unroll
    for (int ct = 0; ct < 2; ct++) {
      bf16x8 bf_ = *(const bf16x8*)(fw2T + (((size_t)n * 32 + ct * 16 + lo) << 9) + k0 + quad * 8);
      acc2[0][ct] = __builtin_amdgcn_mfma_f32_16x16x32_bf16(a0, bf_, acc2[0][ct], 0, 0, 0);
      acc2[1][ct] = __builtin_amdgcn_mfma_f32_16x16x32_bf16(a1f, bf_, acc2[1][ct], 0, 0, 0);
    }
  }
  if (wv == 0) {
#pragma unroll
    for (int rt = 0; rt < 2; rt++)
#pragma unroll
      for (int ct = 0; ct < 2; ct++) {
        int d = ct * 16 + lo;
        float base = fcb[n * 32 + d] + rf[((size_t)n * 16 + b) * 32 + d];
#pragma unroll
        for (int r = 0; r < 4; r++) {
          int row = rt * 16 + quad * 4 + r;
          float v = acc2[rt][ct][r] + base;
          v = v > 0.f ? v : expm1f(v);
          tempb[((size_t)(b * 512 + i0 + row)) * 256 + n * 32 + d] = f2bf(v);
        }
      }
  }
}

// ---------------------------------------------------------------------------
// y = concat([relay, nodes]) rows -> bf16
__global__ __launch_bounds__(256) void build_y_kernel(const float* __restrict__ relay,
                                                      const float* __restrict__ nodes,
                                                      unsigned short* __restrict__ yb) {
  int row = blockIdx.x;
  int b = row / LP1, l = row % LP1;
  const float* src = (l == 0) ? relay + (size_t)b * HH
                              : nodes + ((size_t)b * LL + l - 1) * HH;
  yb[(size_t)row * HH + threadIdx.x] = f2bf(src[threadIdx.x]);
}

__global__ __launch_bounds__(256) void small_gemm_kernel(const float* __restrict__ in,
                                                         const float* __restrict__ WT,
                                                         const float* __restrict__ bias,
                                                         float* __restrict__ out,
                                                         int act) {
  int row = blockIdx.x;
  int t = threadIdx.x;
  __shared__ float xr[256];
  xr[t] = in[(size_t)row * 256 + t];
  __syncthreads();
  float acc = 0.f;
  for (int k = 0; k < 256; k++) acc = fmaf(xr[k], WT[(size_t)k * 256 + t], acc);
  float v = acc + bias[t];
  if (act == 1) v = v > 0.f ? v : 0.01f * v;
  out[(size_t)row * 256 + t] = v;
}

__global__ __launch_bounds__(256) void star_attn_kernel(const float* __restrict__ qstar,
                                                        const float* __restrict__ kt,
                                                        const int* __restrict__ mask,
                                                        float* __restrict__ attstar) {
  int b = blockIdx.x >> 3, n = blockIdx.x & 7;
  int t = threadIdx.x;
  int lane = t & 63, w = t >> 6;
  __shared__ float qv[32];
  __shared__ float pre[LP1];
  __shared__ float red[4];
  __shared__ float par[8][33];
  if (t < 32) qv[t] = qstar[b * 256 + n * 32 + t];
  __syncthreads();
  const float scale = 0.17677669529663687f;
  for (int l = t; l < LP1; l += 256) {
    bool masked = (l > 0) && (mask[b * LL + l - 1] == 0);
    float p;
    if (masked) p = -3.4e38f;
    else {
      p = 0.f;
      const float* krow = kt + ((size_t)b * LP1 + l) * 256 + n * 32;
      for (int d = 0; d < 32; d++) p = fmaf(qv[d], krow[d], p);
      p *= scale;
    }
    pre[l] = p;
  }
  __syncthreads();
  float m = -3.4e38f;
  for (int l = t; l < LP1; l += 256) m = fmaxf(m, pre[l]);
#pragma unroll
  for (int o = 32; o; o >>= 1) m = fmaxf(m, __shfl_xor(m, o));
  if (lane == 0) red[w] = m;
  __syncthreads();
  m = fmaxf(fmaxf(red[0], red[1]), fmaxf(red[2], red[3]));
  __syncthreads();
  float s = 0.f;
  for (int l = t; l < LP1; l += 256) {
    float wv = __expf(pre[l] - m);
    pre[l] = wv;
    s += wv;
  }
#pragma unroll
  for (int o = 32; o; o >>= 1) s += __shfl_xor(s, o);
  if (lane == 0) red[w] = s;
  __syncthreads();
  float denom = red[0] + red[1] + red[2] + red[3];
  int d = t & 31, g = t >> 5;
  float acc = 0.f;
  for (int l = g; l < LP1; l += 8)
    acc = fmaf(pre[l], kt[((size_t)b * LP1 + l) * 256 + n * 32 + d], acc);
  par[g][d] = acc;
  __syncthreads();
  if (t < 32) {
    float a = 0.f;
    for (int gg = 0; gg < 8; gg++) a += par[gg][t];
    attstar[b * 256 + n * 32 + t] = a / denom;
  }
}

// ---------------------------------------------------------------------------
extern "C" void kernel_launch(void* const* d_in, const int* in_sizes, int n_in,
                              void* d_out, int out_size, void* d_ws, size_t ws_size,
                              hipStream_t stream) {
  const float* data  = (const float*)d_in[0];
  const float* WQw   = (const float*)d_in[1];
  const float* WQb   = (const float*)d_in[2];
  const float* a1    = (const float*)d_in[3];
  const float* a2    = (const float*)d_in[4];
  const float* fcw_g = (const float*)d_in[5];
  const float* fcb_g = (const float*)d_in[6];
  const float* ng    = (const float*)d_in[7];
  const float* nb    = (const float*)d_in[8];
  const float* sq_w  = (const float*)d_in[9];
  const float* sq_b  = (const float*)d_in[10];
  const float* sk_w  = (const float*)d_in[11];
  const float* sk_b  = (const float*)d_in[12];
  const float* so_w  = (const float*)d_in[13];
  const float* so_b  = (const float*)d_in[14];
  const float* fc_w  = (const float*)d_in[15];
  const float* fc_b  = (const float*)d_in[16];
  const int*   mask  = (const int*)d_in[17];
  const int*   edge  = (const int*)d_in[18];

  float* nodes = (float*)d_out;
  float* relay = nodes + NODES_ELEMS;

  char* p = (char*)d_ws;
  auto alloc = [&](size_t bytes) -> char* {
    char* r = p; p += (bytes + 255) & ~(size_t)255; return r;
  };
  float* xn            = (float*)alloc((size_t)8192 * 256 * 4);
  unsigned short* xnb  = (unsigned short*)alloc((size_t)8192 * 256 * 2);
  unsigned short* qxT  = (unsigned short*)alloc((size_t)8 * 16 * 256 * 512 * 2);
  unsigned short* dTb  = (unsigned short*)alloc((size_t)16 * 256 * 512 * 2);
  unsigned short* tmpb = (unsigned short*)alloc((size_t)8192 * 256 * 2);
  unsigned short* yb   = (unsigned short*)alloc((size_t)8208 * 256 * 2);
  float* kt            = (float*)alloc((size_t)8208 * 256 * 4);
  float* ei            = (float*)alloc(65536 * 4);
  float* ej            = (float*)alloc(65536 * 4);
  float* ra1           = (float*)alloc(128 * 4);
  float* ra2           = (float*)alloc(128 * 4);
  float* rf            = (float*)alloc(4096 * 4);
  float* w1            = (float*)alloc(2048 * 4);
  float* w2            = (float*)alloc(2048 * 4);
  float* c1            = (float*)alloc(8 * 4);
  float* c2            = (float*)alloc(8 * 4);
  unsigned short* wqb  = (unsigned short*)alloc((size_t)524288 * 2);
  unsigned short* fcwT = (unsigned short*)alloc((size_t)65536 * 2);
  unsigned short* skwb = (unsigned short*)alloc((size_t)131072 * 2);
  unsigned short* fw2T = (unsigned short*)alloc((size_t)131072 * 2);
  float* sqT           = (float*)alloc((size_t)131072 * 4);
  float* soT           = (float*)alloc((size_t)131072 * 4);
  float* qst           = (float*)alloc(4096 * 4);
  float* atts          = (float*)alloc(4096 * 4);

  hipMemcpyAsync(nodes, data, (size_t)NODES_ELEMS * sizeof(float),
                 hipMemcpyDeviceToDevice, stream);
  init_relay_kernel<<<BB, 256, 0, stream>>>(data, relay);

  // one-time precomputes
  cvt_bf16_kernel<<<2048, 256, 0, stream>>>(WQw, wqb, 524288);
  w12_kernel<<<8, 256, 0, stream>>>(WQw, WQb, a1, a2, w1, w2, c1, c2);
  fw2T_kernel<<<512, 256, 0, stream>>>(fcw_g, fw2T);
  fcwT_kernel<<<256, 256, 0, stream>>>(fc_w, fcwT);
  cvt_bf16_kernel<<<512, 256, 0, stream>>>(sk_w, skwb, 131072);
  dataT_kernel<<<dim3(16, 8, 16), dim3(32, 32), 0, stream>>>(data, dTb);
  for (int it = 0; it < 2; it++) {
    transpose_kernel<<<256, 256, 0, stream>>>(sq_w + it * 65536, sqT + it * 65536, 256, 256);
    transpose_kernel<<<256, 256, 0, stream>>>(so_w + it * 65536, soT + it * 65536, 256, 256);
  }

  for (int it = 0; it < 2; it++) {
    ln_kernel<<<BB * LL, 256, 0, stream>>>(nodes, ng + it * 256, nb + it * 256, xn, xnb);
    rarf_kernel<<<NHEAD * BB, 256, 0, stream>>>(relay, a1, a2, fcw_g, ra1, ra2, rf);
    eiej2_kernel<<<NHEAD * BB * LL, 64, 0, stream>>>(xn, data, w1, w2, a1, a2,
                                                     c1, c2, ra1, ra2, ei, ej);
    // qx = xn @ WqT + bq  ->  qxT bf16 (head-transposed)
    mfma_gemm_kernel<<<dim3(32, 128), 256, 0, stream>>>(xnb, wqb, WQb, 8192, 0,
                                                        nullptr, qxT, nullptr, nullptr);
    gat_mfma_kernel<<<NHEAD * BB * 16, 256, 0, stream>>>(qxT, dTb, ei, ej, edge,
                                                         fw2T, fcb_g, rf, tmpb);
    // nodes = mask ? nodes + lrelu(temp @ fc_w + fc_b) : 0
    mfma_gemm_kernel<<<dim3(4, 128), 256, 0, stream>>>(tmpb, fcwT, fc_b, 8192, 1,
                                                       nodes, nullptr, nodes, mask);
    build_y_kernel<<<BB * LP1, 256, 0, stream>>>(relay, nodes, yb);
    // kt = y @ sk_wT + sk_b
    mfma_gemm_kernel<<<dim3(4, 129), 256, 0, stream>>>(yb, skwb + it * 65536,
                                                       sk_b + it * 256, 8208, 2,
                                                       kt, nullptr, nullptr, nullptr);
    small_gemm_kernel<<<BB, 256, 0, stream>>>(relay, sqT + it * 65536, sq_b + it * 256,
                                              qst, 0);
    star_attn_kernel<<<BB * NHEAD, 256, 0, stream>>>(qst, kt, mask, atts);
    small_gemm_kernel<<<BB, 256, 0, stream>>>(atts, soT + it * 65536, so_b + it * 256,
                                              relay, 1);
  }
}

// Round 3
// 752.243 us; speedup vs baseline: 2.8362x; 1.1440x over previous
//
#include <hip/hip_runtime.h>
#include <hip/hip_bf16.h>
#include <math.h>

#define BB 16
#define LL 512
#define HH 256
#define NHEAD 8
#define HDIM 32
#define LP1 513
#define NHHD 256
#define NODES_ELEMS (BB*LL*HH)

typedef __attribute__((ext_vector_type(8))) short bf16x8;
typedef __attribute__((ext_vector_type(4))) float f32x4;

__device__ __forceinline__ unsigned short f2bf(float f) {
  union { float f; unsigned u; } x; x.f = f;
  unsigned r = x.u + 0x7fffu + ((x.u >> 16) & 1u);
  return (unsigned short)(r >> 16);
}

// ---------------------------------------------------------------------------
__global__ __launch_bounds__(256) void init_relay_kernel(const float* __restrict__ data,
                                                         float* __restrict__ relay) {
  int b = blockIdx.x, t = threadIdx.x;
  float s = 0.f;
  const float* p = data + (size_t)b * LL * HH + t;
  for (int l = 0; l < LL; l++) s += p[(size_t)l * HH];
  relay[b * HH + t] = s * (1.0f / 512.0f);
}

__global__ __launch_bounds__(256) void transpose_kernel(const float* __restrict__ in,
                                                        float* __restrict__ out,
                                                        int R, int C) {
  int idx = blockIdx.x * 256 + threadIdx.x;
  if (idx < R * C) {
    int r = idx / C, c = idx % C;
    out[(size_t)c * R + r] = in[idx];
  }
}

__global__ __launch_bounds__(256) void cvt_bf16_kernel(const float* __restrict__ in,
                                                       unsigned short* __restrict__ out,
                                                       int n) {
  int idx = blockIdx.x * 256 + threadIdx.x;
  if (idx < n) out[idx] = f2bf(in[idx]);
}

// fc_w [256 k][256 o] -> fcwT[o][k] bf16
__global__ __launch_bounds__(256) void fcwT_kernel(const float* __restrict__ in,
                                                   unsigned short* __restrict__ out) {
  int idx = blockIdx.x * 256 + threadIdx.x;   // idx = o*256 + k
  int o = idx >> 8, k = idx & 255;
  out[idx] = f2bf(in[k * 256 + o]);
}

// fw2T[n][d][c] = Fw[n][c<256 ? c : 2c-256][d] bf16
__global__ __launch_bounds__(256) void fw2T_kernel(const float* __restrict__ fcw,
                                                   unsigned short* __restrict__ out) {
  int idx = blockIdx.x * 256 + threadIdx.x;   // ((n*32+d)*512)+c
  int c = idx & 511, d = (idx >> 9) & 31, n = idx >> 14;
  int srow = (c < 256) ? c : (2 * c - 256);
  out[idx] = f2bf(fcw[((size_t)n * 768 + srow) * 32 + d]);
}

// dataT[b][c][j] bf16 from data[b][j][c]
__global__ void dataT_kernel(const float* __restrict__ data,
                             unsigned short* __restrict__ dataT) {
  __shared__ float tile[32][33];
  int b = blockIdx.z, j0 = blockIdx.x * 32, c0 = blockIdx.y * 32;
  tile[threadIdx.y][threadIdx.x] =
      data[((size_t)(b * 512 + j0 + threadIdx.y)) * 256 + c0 + threadIdx.x];
  __syncthreads();
  dataT[((size_t)(b * 256 + c0 + threadIdx.y)) * 512 + j0 + threadIdx.x] =
      f2bf(tile[threadIdx.x][threadIdx.y]);
}

// w1[n][k] = sum_c a1[n][c]*WQw[n][c][k]; c1[n] = sum_c a1[n][c]*WQb[n][c]
__global__ __launch_bounds__(256) void w12_kernel(const float* __restrict__ WQw,
                                                  const float* __restrict__ WQb,
                                                  const float* __restrict__ a1,
                                                  const float* __restrict__ a2,
                                                  float* __restrict__ w1,
                                                  float* __restrict__ w2,
                                                  float* __restrict__ c1,
                                                  float* __restrict__ c2) {
  int n = blockIdx.x, t = threadIdx.x;
  float s1 = 0.f, s2 = 0.f;
  for (int c = 0; c < 256; c++) {
    float wv = WQw[((size_t)(n * 256 + c)) * 256 + t];
    s1 = fmaf(a1[n * 768 + c], wv, s1);
    s2 = fmaf(a2[n * 768 + c], wv, s2);
  }
  w1[n * 256 + t] = s1;
  w2[n * 256 + t] = s2;
  __shared__ float r1[256], r2[256];
  r1[t] = a1[n * 768 + t] * WQb[n * 256 + t];
  r2[t] = a2[n * 768 + t] * WQb[n * 256 + t];
  __syncthreads();
  for (int o = 128; o; o >>= 1) {
    if (t < o) { r1[t] += r1[t + o]; r2[t] += r2[t + o]; }
    __syncthreads();
  }
  if (t == 0) { c1[n] = r1[0]; c2[n] = r2[0]; }
}

// ---------------------------------------------------------------------------
__global__ __launch_bounds__(256) void ln_kernel(const float* __restrict__ nodes,
                                                 const float* __restrict__ g,
                                                 const float* __restrict__ bb,
                                                 float* __restrict__ xn,
                                                 unsigned short* __restrict__ xnb) {
  int row = blockIdx.x;
  int t = threadIdx.x;
  int lane = t & 63, w = t >> 6;
  __shared__ float red[4];
  float x = nodes[(size_t)row * HH + t];
  float s = x;
#pragma unroll
  for (int o = 32; o; o >>= 1) s += __shfl_xor(s, o);
  if (lane == 0) red[w] = s;
  __syncthreads();
  float mean = (red[0] + red[1] + red[2] + red[3]) * (1.0f / 256.0f);
  __syncthreads();
  float d = x - mean;
  float v = d * d;
#pragma unroll
  for (int o = 32; o; o >>= 1) v += __shfl_xor(v, o);
  if (lane == 0) red[w] = v;
  __syncthreads();
  float var = (red[0] + red[1] + red[2] + red[3]) * (1.0f / 256.0f);
  float rstd = rsqrtf(var + 1e-5f);
  float out = d * rstd * g[t] + bb[t];
  xn[(size_t)row * HH + t] = out;
  xnb[(size_t)row * HH + t] = f2bf(out);
}

__global__ __launch_bounds__(256) void rarf_kernel(const float* __restrict__ relay,
                                                   const float* __restrict__ a1,
                                                   const float* __restrict__ a2,
                                                   const float* __restrict__ fcw,
                                                   float* __restrict__ ra1,
                                                   float* __restrict__ ra2,
                                                   float* __restrict__ rf) {
  int n = blockIdx.x >> 4, b = blockIdx.x & 15;
  int t = threadIdx.x;
  int lane = t & 63, w = t >> 6;
  __shared__ float rel[256];
  __shared__ float red1[4], red2[4];
  __shared__ float pf_s[8][33];
  rel[t] = relay[b * HH + t];
  __syncthreads();
  float p1 = rel[t] * a1[n * 768 + 257 + 2 * t];
  float p2 = rel[t] * a2[n * 768 + 257 + 2 * t];
#pragma unroll
  for (int o = 32; o; o >>= 1) { p1 += __shfl_xor(p1, o); p2 += __shfl_xor(p2, o); }
  if (lane == 0) { red1[w] = p1; red2[w] = p2; }
  int d = t & 31, seg = t >> 5;
  float pf = 0.f;
  for (int u = 0; u < 32; u++) {
    int k = seg * 32 + u;
    pf = fmaf(rel[k], fcw[((size_t)n * 768 + 257 + 2 * k) * 32 + d], pf);
  }
  pf_s[seg][d] = pf;
  __syncthreads();
  if (t == 0) {
    ra1[n * 16 + b] = red1[0] + red1[1] + red1[2] + red1[3];
    ra2[n * 16 + b] = red2[0] + red2[1] + red2[2] + red2[3];
  }
  if (t < 32) {
    float s = 0.f;
    for (int gg = 0; gg < 8; gg++) s += pf_s[gg][t];
    rf[((size_t)n * 16 + b) * 32 + t] = s;
  }
}

// ei/ej: 4 waves per block, one row each
__global__ __launch_bounds__(256) void eiej2_kernel(const float* __restrict__ xn,
                                                   const float* __restrict__ data,
                                                   const float* __restrict__ w1,
                                                   const float* __restrict__ w2,
                                                   const float* __restrict__ a1,
                                                   const float* __restrict__ a2,
                                                   const float* __restrict__ c1,
                                                   const float* __restrict__ c2,
                                                   const float* __restrict__ ra1,
                                                   const float* __restrict__ ra2,
                                                   float* __restrict__ ei,
                                                   float* __restrict__ ej) {
  int id = blockIdx.x * 4 + (threadIdx.x >> 6);   // n*8192 + b*512 + l
  int n = id >> 13;
  int r = id & 8191;
  int b = r >> 9;
  int lane = threadIdx.x & 63;
  const float* xr = xn + (size_t)r * 256;
  const float* dr = data + (size_t)r * 256;
  float s1 = 0.f, s2 = 0.f;
#pragma unroll
  for (int u = 0; u < 4; u++) {
    int c = lane + 64 * u;
    float xv = xr[c], dv = dr[c];
    s1 = fmaf(xv, w1[n * 256 + c], s1);
    s1 = fmaf(dv, a1[n * 768 + 256 + 2 * c], s1);
    s2 = fmaf(xv, w2[n * 256 + c], s2);
    s2 = fmaf(dv, a2[n * 768 + 256 + 2 * c], s2);
  }
#pragma unroll
  for (int o = 32; o; o >>= 1) { s1 += __shfl_xor(s1, o); s2 += __shfl_xor(s2, o); }
  if (lane == 0) {
    ei[id] = s1 + c1[n] + ra1[n * 16 + b];
    ej[id] = s2 + c2[n] + ra2[n * 16 + b];
  }
}

// ---------------------------------------------------------------------------
// MFMA GEMM over K=256 bf16, M-tile 128 (2 row-tiles/wave), N-tile 64
__global__ __launch_bounds__(256) void mfma_gemm_kernel(
    const unsigned short* __restrict__ A, const unsigned short* __restrict__ Bw,
    const float* __restrict__ bias, int Mvalid, int mode,
    float* __restrict__ outF, unsigned short* __restrict__ outT,
    const float* __restrict__ resid, const int* __restrict__ mask) {
  int tileN = blockIdx.x * 64;
  int tileM = blockIdx.y * 128;
  int t = threadIdx.x;
  int wv = t >> 6, lane = t & 63;
  int lo = lane & 15, quad = lane >> 4;
  int rowBase0 = tileM + wv * 32;
  const unsigned short* aptr[2];
#pragma unroll
  for (int rt = 0; rt < 2; rt++) {
    int arow = rowBase0 + rt * 16 + lo;
    if (arow >= Mvalid) arow = Mvalid - 1;
    aptr[rt] = A + (size_t)arow * 256 + quad * 8;
  }
  f32x4 acc[2][4] = {};
  for (int k0 = 0; k0 < 256; k0 += 32) {
    bf16x8 af[2];
#pragma unroll
    for (int rt = 0; rt < 2; rt++) af[rt] = *(const bf16x8*)(aptr[rt] + k0);
#pragma unroll
    for (int ct = 0; ct < 4; ct++) {
      bf16x8 bf_ = *(const bf16x8*)(Bw + (size_t)(tileN + ct * 16 + lo) * 256 + k0 + quad * 8);
#pragma unroll
      for (int rt = 0; rt < 2; rt++)
        acc[rt][ct] = __builtin_amdgcn_mfma_f32_16x16x32_bf16(af[rt], bf_, acc[rt][ct], 0, 0, 0);
    }
  }
#pragma unroll
  for (int rt = 0; rt < 2; rt++) {
    int rowBase = rowBase0 + rt * 16;
#pragma unroll
    for (int ct = 0; ct < 4; ct++) {
      int co = tileN + ct * 16 + lo;
      float bv = bias[co];
      if (mode == 0) {
        int jrow = rowBase + quad * 4;
        int bb2 = jrow >> 9, jj = jrow & 511;
        int hn = co >> 8, cc = co & 255;
        ushort4 pk;
        pk.x = f2bf(acc[rt][ct][0] + bv);
        pk.y = f2bf(acc[rt][ct][1] + bv);
        pk.z = f2bf(acc[rt][ct][2] + bv);
        pk.w = f2bf(acc[rt][ct][3] + bv);
        *(ushort4*)&outT[(((size_t)(hn * 16 + bb2) * 256 + cc) << 9) + jj] = pk;
      } else {
#pragma unroll
        for (int r = 0; r < 4; r++) {
          int row = rowBase + quad * 4 + r;
          if (row >= Mvalid) continue;
          float v = acc[rt][ct][r] + bv;
          if (mode == 1) {
            v = v > 0.f ? v : 0.01f * v;
            v = (mask[row] != 0) ? resid[(size_t)row * 256 + co] + v : 0.f;
          }
          outF[(size_t)row * 256 + co] = v;
        }
      }
    }
  }
}

// ---------------------------------------------------------------------------
// GAT fused: softmax -> MFMA aggregation (M=64) -> MFMA output proj
// block: (n, b, 64 rows), 256 threads / 4 waves
__global__ __launch_bounds__(256) void gat_mfma_kernel(
    const unsigned short* __restrict__ qxT,   // [8][16][256][512] bf16
    const unsigned short* __restrict__ dataT, // [16][256][512] bf16
    const float* __restrict__ ei, const float* __restrict__ ej,
    const int* __restrict__ edge,
    const unsigned short* __restrict__ fw2T,  // [8][32][512] bf16
    const float* __restrict__ fcb, const float* __restrict__ rf,
    unsigned short* __restrict__ tempb) {     // [8192][256] bf16
  __shared__ unsigned short W[64][512];       // 64KB: att weights, then hp (swizzled)
  int blk = blockIdx.x;
  int n = blk >> 7;
  int b = (blk >> 3) & 15;
  int i0 = (blk & 7) << 6;
  int t = threadIdx.x;
  int wv = t >> 6, lane = t & 63;
  int lo = lane & 15, quad = lane >> 4;

  // ---- Phase A: softmax for rows wv*16 .. wv*16+15
  const float* ejrow = ej + n * 8192 + b * 512;
  float ejv[8];
#pragma unroll
  for (int u = 0; u < 8; u++) ejv[u] = ejrow[lane + 64 * u];
  for (int rr = 0; rr < 16; rr++) {
    int row = wv * 16 + rr;
    float eiv = ei[n * 8192 + b * 512 + i0 + row];
    const int* adj = edge + (((size_t)b * 512 + i0 + row) << 9);
    float evv[8];
    float m = -3.0e38f;
#pragma unroll
    for (int u = 0; u < 8; u++) {
      int j = lane + 64 * u;
      float e;
      if (adj[j] > 0) { e = eiv + ejv[u]; e = e > 0.f ? e : 0.2f * e; }
      else e = -9.0e15f;
      evv[u] = e;
      m = fmaxf(m, e);
    }
#pragma unroll
    for (int o = 32; o; o >>= 1) m = fmaxf(m, __shfl_xor(m, o));
    float s = 0.f;
#pragma unroll
    for (int u = 0; u < 8; u++) {
      float wexp = __expf(evv[u] - m);
      evv[u] = wexp;
      s += wexp;
    }
#pragma unroll
    for (int o = 32; o; o >>= 1) s += __shfl_xor(s, o);
    float inv = 1.0f / s;
#pragma unroll
    for (int u = 0; u < 8; u++) W[row][lane + 64 * u] = f2bf(evv[u] * inv);
  }
  __syncthreads();

  // ---- Phase B: hp[64 rows, 512 cols] = W @ H; wave wv owns 128 cols
  const unsigned short* hbase =
      (wv < 2) ? qxT + (((size_t)(n * 16 + b)) * 256 + wv * 128) * 512
               : dataT + (((size_t)b) * 256 + (wv - 2) * 128) * 512;
  f32x4 acc[4][8] = {};
  for (int j0 = 0; j0 < 512; j0 += 32) {
    bf16x8 af[4];
#pragma unroll
    for (int rt = 0; rt < 4; rt++)
      af[rt] = *(const bf16x8*)&W[rt * 16 + lo][j0 + quad * 8];  // broadcast reads
#pragma unroll
    for (int ct = 0; ct < 8; ct++) {
      bf16x8 bf_ = *(const bf16x8*)(hbase + ((size_t)(ct * 16 + lo)) * 512 + j0 + quad * 8);
#pragma unroll
      for (int rt = 0; rt < 4; rt++)
        acc[rt][ct] = __builtin_amdgcn_mfma_f32_16x16x32_bf16(af[rt], bf_, acc[rt][ct], 0, 0, 0);
    }
  }
  __syncthreads();   // done reading W

  // park hp bf16 in LDS, XOR-swizzled 8-short chunks: chunk' = chunk ^ (row&7)
#pragma unroll
  for (int rt = 0; rt < 4; rt++)
#pragma unroll
    for (int ct = 0; ct < 8; ct++) {
      int c = wv * 128 + ct * 16 + lo;
      int chunk = c >> 3, within = c & 7;
#pragma unroll
      for (int r = 0; r < 4; r++) {
        int row = rt * 16 + quad * 4 + r;
        W[row][((chunk ^ (row & 7)) << 3) + within] = f2bf(acc[rt][ct][r]);
      }
    }
  __syncthreads();

  // ---- Phase C: out[64 rows, 32 d] = hp @ fw2; wave wv owns row-tile wv
  f32x4 acc2[2] = {};
  {
    int arow = wv * 16 + lo;
    int rx = arow & 7;
    for (int k0 = 0; k0 < 512; k0 += 32) {
      int chunk = (k0 >> 3) + quad;
      bf16x8 a0 = *(const bf16x8*)&W[arow][(chunk ^ rx) << 3];
#pragma unroll
      for (int ct = 0; ct < 2; ct++) {
        bf16x8 bf_ = *(const bf16x8*)(fw2T + (((size_t)n * 32 + ct * 16 + lo) << 9) + k0 + quad * 8);
        acc2[ct] = __builtin_amdgcn_mfma_f32_16x16x32_bf16(a0, bf_, acc2[ct], 0, 0, 0);
      }
    }
  }
#pragma unroll
  for (int ct = 0; ct < 2; ct++) {
    int d = ct * 16 + lo;
    float base = fcb[n * 32 + d] + rf[((size_t)n * 16 + b) * 32 + d];
#pragma unroll
    for (int r = 0; r < 4; r++) {
      int row = wv * 16 + quad * 4 + r;
      float v = acc2[ct][r] + base;
      v = v > 0.f ? v : expm1f(v);
      tempb[((size_t)(b * 512 + i0 + row)) * 256 + n * 32 + d] = f2bf(v);
    }
  }
}

// ---------------------------------------------------------------------------
__global__ __launch_bounds__(256) void build_y_kernel(const float* __restrict__ relay,
                                                      const float* __restrict__ nodes,
                                                      unsigned short* __restrict__ yb) {
  int row = blockIdx.x;
  int b = row / LP1, l = row % LP1;
  const float* src = (l == 0) ? relay + (size_t)b * HH
                              : nodes + ((size_t)b * LL + l - 1) * HH;
  yb[(size_t)row * HH + threadIdx.x] = f2bf(src[threadIdx.x]);
}

__global__ __launch_bounds__(256) void small_gemm_kernel(const float* __restrict__ in,
                                                         const float* __restrict__ WT,
                                                         const float* __restrict__ bias,
                                                         float* __restrict__ out,
                                                         int act) {
  int row = blockIdx.x;
  int t = threadIdx.x;
  __shared__ float xr[256];
  xr[t] = in[(size_t)row * 256 + t];
  __syncthreads();
  float acc = 0.f;
  for (int k = 0; k < 256; k++) acc = fmaf(xr[k], WT[(size_t)k * 256 + t], acc);
  float v = acc + bias[t];
  if (act == 1) v = v > 0.f ? v : 0.01f * v;
  out[(size_t)row * 256 + t] = v;
}

__global__ __launch_bounds__(256) void star_attn_kernel(const float* __restrict__ qstar,
                                                        const float* __restrict__ kt,
                                                        const int* __restrict__ mask,
                                                        float* __restrict__ attstar) {
  int b = blockIdx.x >> 3, n = blockIdx.x & 7;
  int t = threadIdx.x;
  int lane = t & 63, w = t >> 6;
  __shared__ float qv[32];
  __shared__ float pre[LP1];
  __shared__ float red[4];
  __shared__ float par[8][33];
  if (t < 32) qv[t] = qstar[b * 256 + n * 32 + t];
  __syncthreads();
  const float scale = 0.17677669529663687f;
  for (int l = t; l < LP1; l += 256) {
    bool masked = (l > 0) && (mask[b * LL + l - 1] == 0);
    float p;
    if (masked) p = -3.4e38f;
    else {
      p = 0.f;
      const float* krow = kt + ((size_t)b * LP1 + l) * 256 + n * 32;
      for (int d = 0; d < 32; d++) p = fmaf(qv[d], krow[d], p);
      p *= scale;
    }
    pre[l] = p;
  }
  __syncthreads();
  float m = -3.4e38f;
  for (int l = t; l < LP1; l += 256) m = fmaxf(m, pre[l]);
#pragma unroll
  for (int o = 32; o; o >>= 1) m = fmaxf(m, __shfl_xor(m, o));
  if (lane == 0) red[w] = m;
  __syncthreads();
  m = fmaxf(fmaxf(red[0], red[1]), fmaxf(red[2], red[3]));
  __syncthreads();
  float s = 0.f;
  for (int l = t; l < LP1; l += 256) {
    float wv = __expf(pre[l] - m);
    pre[l] = wv;
    s += wv;
  }
#pragma unroll
  for (int o = 32; o; o >>= 1) s += __shfl_xor(s, o);
  if (lane == 0) red[w] = s;
  __syncthreads();
  float denom = red[0] + red[1] + red[2] + red[3];
  int d = t & 31, g = t >> 5;
  float acc = 0.f;
  for (int l = g; l < LP1; l += 8)
    acc = fmaf(pre[l], kt[((size_t)b * LP1 + l) * 256 + n * 32 + d], acc);
  par[g][d] = acc;
  __syncthreads();
  if (t < 32) {
    float a = 0.f;
    for (int gg = 0; gg < 8; gg++) a += par[gg][t];
    attstar[b * 256 + n * 32 + t] = a / denom;
  }
}

// ---------------------------------------------------------------------------
extern "C" void kernel_launch(void* const* d_in, const int* in_sizes, int n_in,
                              void* d_out, int out_size, void* d_ws, size_t ws_size,
                              hipStream_t stream) {
  const float* data  = (const float*)d_in[0];
  const float* WQw   = (const float*)d_in[1];
  const float* WQb   = (const float*)d_in[2];
  const float* a1    = (const float*)d_in[3];
  const float* a2    = (const float*)d_in[4];
  const float* fcw_g = (const float*)d_in[5];
  const float* fcb_g = (const float*)d_in[6];
  const float* ng    = (const float*)d_in[7];
  const float* nb    = (const float*)d_in[8];
  const float* sq_w  = (const float*)d_in[9];
  const float* sq_b  = (const float*)d_in[10];
  const float* sk_w  = (const float*)d_in[11];
  const float* sk_b  = (const float*)d_in[12];
  const float* so_w  = (const float*)d_in[13];
  const float* so_b  = (const float*)d_in[14];
  const float* fc_w  = (const float*)d_in[15];
  const float* fc_b  = (const float*)d_in[16];
  const int*   mask  = (const int*)d_in[17];
  const int*   edge  = (const int*)d_in[18];

  float* nodes = (float*)d_out;
  float* relay = nodes + NODES_ELEMS;

  char* p = (char*)d_ws;
  auto alloc = [&](size_t bytes) -> char* {
    char* r = p; p += (bytes + 255) & ~(size_t)255; return r;
  };
  float* xn            = (float*)alloc((size_t)8192 * 256 * 4);
  unsigned short* xnb  = (unsigned short*)alloc((size_t)8192 * 256 * 2);
  unsigned short* qxT  = (unsigned short*)alloc((size_t)8 * 16 * 256 * 512 * 2);
  unsigned short* dTb  = (unsigned short*)alloc((size_t)16 * 256 * 512 * 2);
  unsigned short* tmpb = (unsigned short*)alloc((size_t)8192 * 256 * 2);
  unsigned short* yb   = (unsigned short*)alloc((size_t)8208 * 256 * 2);
  float* kt            = (float*)alloc((size_t)8208 * 256 * 4);
  float* ei            = (float*)alloc(65536 * 4);
  float* ej            = (float*)alloc(65536 * 4);
  float* ra1           = (float*)alloc(128 * 4);
  float* ra2           = (float*)alloc(128 * 4);
  float* rf            = (float*)alloc(4096 * 4);
  float* w1            = (float*)alloc(2048 * 4);
  float* w2            = (float*)alloc(2048 * 4);
  float* c1            = (float*)alloc(8 * 4);
  float* c2            = (float*)alloc(8 * 4);
  unsigned short* wqb  = (unsigned short*)alloc((size_t)524288 * 2);
  unsigned short* fcwT = (unsigned short*)alloc((size_t)65536 * 2);
  unsigned short* skwb = (unsigned short*)alloc((size_t)131072 * 2);
  unsigned short* fw2T = (unsigned short*)alloc((size_t)131072 * 2);
  float* sqT           = (float*)alloc((size_t)131072 * 4);
  float* soT           = (float*)alloc((size_t)131072 * 4);
  float* qst           = (float*)alloc(4096 * 4);
  float* atts          = (float*)alloc(4096 * 4);

  hipMemcpyAsync(nodes, data, (size_t)NODES_ELEMS * sizeof(float),
                 hipMemcpyDeviceToDevice, stream);
  init_relay_kernel<<<BB, 256, 0, stream>>>(data, relay);

  // one-time precomputes
  cvt_bf16_kernel<<<2048, 256, 0, stream>>>(WQw, wqb, 524288);
  w12_kernel<<<8, 256, 0, stream>>>(WQw, WQb, a1, a2, w1, w2, c1, c2);
  fw2T_kernel<<<512, 256, 0, stream>>>(fcw_g, fw2T);
  fcwT_kernel<<<256, 256, 0, stream>>>(fc_w, fcwT);
  cvt_bf16_kernel<<<512, 256, 0, stream>>>(sk_w, skwb, 131072);
  dataT_kernel<<<dim3(16, 8, 16), dim3(32, 32), 0, stream>>>(data, dTb);
  for (int it = 0; it < 2; it++) {
    transpose_kernel<<<256, 256, 0, stream>>>(sq_w + it * 65536, sqT + it * 65536, 256, 256);
    transpose_kernel<<<256, 256, 0, stream>>>(so_w + it * 65536, soT + it * 65536, 256, 256);
  }

  for (int it = 0; it < 2; it++) {
    ln_kernel<<<BB * LL, 256, 0, stream>>>(nodes, ng + it * 256, nb + it * 256, xn, xnb);
    rarf_kernel<<<NHEAD * BB, 256, 0, stream>>>(relay, a1, a2, fcw_g, ra1, ra2, rf);
    eiej2_kernel<<<NHEAD * BB * LL / 4, 256, 0, stream>>>(xn, data, w1, w2, a1, a2,
                                                          c1, c2, ra1, ra2, ei, ej);
    // qx = xn @ WqT + bq  ->  qxT bf16 (head-transposed)
    mfma_gemm_kernel<<<dim3(32, 64), 256, 0, stream>>>(xnb, wqb, WQb, 8192, 0,
                                                       nullptr, qxT, nullptr, nullptr);
    gat_mfma_kernel<<<NHEAD * BB * 8, 256, 0, stream>>>(qxT, dTb, ei, ej, edge,
                                                        fw2T, fcb_g, rf, tmpb);
    // nodes = mask ? nodes + lrelu(temp @ fc_w + fc_b) : 0
    mfma_gemm_kernel<<<dim3(4, 64), 256, 0, stream>>>(tmpb, fcwT, fc_b, 8192, 1,
                                                      nodes, nullptr, nodes, mask);
    build_y_kernel<<<BB * LP1, 256, 0, stream>>>(relay, nodes, yb);
    // kt = y @ sk_wT + sk_b
    mfma_gemm_kernel<<<dim3(4, 65), 256, 0, stream>>>(yb, skwb + it * 65536,
                                                      sk_b + it * 256, 8208, 2,
                                                      kt, nullptr, nullptr, nullptr);
    small_gemm_kernel<<<BB, 256, 0, stream>>>(relay, sqT + it * 65536, sq_b + it * 256,
                                              qst, 0);
    star_attn_kernel<<<BB * NHEAD, 256, 0, stream>>>(qst, kt, mask, atts);
    small_gemm_kernel<<<BB, 256, 0, stream>>>(atts, soT + it * 65536, so_b + it * 256,
                                              relay, 1);
  }
}

// Round 4
// 517.332 us; speedup vs baseline: 4.1241x; 1.4541x over previous
//
#include <hip/hip_runtime.h>
#include <hip/hip_bf16.h>
#include <math.h>

#define BB 16
#define LL 512
#define HH 256
#define NHEAD 8
#define HDIM 32
#define LP1 513
#define NHHD 256
#define NODES_ELEMS (BB*LL*HH)

typedef __attribute__((ext_vector_type(8))) short bf16x8;
typedef __attribute__((ext_vector_type(4))) float f32x4;

__device__ __forceinline__ unsigned short f2bf(float f) {
  union { float f; unsigned u; } x; x.f = f;
  unsigned r = x.u + 0x7fffu + ((x.u >> 16) & 1u);
  return (unsigned short)(r >> 16);
}

// ---------------------------------------------------------------------------
__global__ __launch_bounds__(256) void init_relay_kernel(const float* __restrict__ data,
                                                         float* __restrict__ relay) {
  int b = blockIdx.x, t = threadIdx.x;
  float s = 0.f;
  const float* p = data + (size_t)b * LL * HH + t;
  for (int l = 0; l < LL; l++) s += p[(size_t)l * HH];
  relay[b * HH + t] = s * (1.0f / 512.0f);
}

__global__ __launch_bounds__(256) void transpose_kernel(const float* __restrict__ in,
                                                        float* __restrict__ out,
                                                        int R, int C) {
  int idx = blockIdx.x * 256 + threadIdx.x;
  if (idx < R * C) {
    int r = idx / C, c = idx % C;
    out[(size_t)c * R + r] = in[idx];
  }
}

__global__ __launch_bounds__(256) void cvt_bf16_kernel(const float* __restrict__ in,
                                                       unsigned short* __restrict__ out,
                                                       int n) {
  int idx = blockIdx.x * 256 + threadIdx.x;
  if (idx < n) out[idx] = f2bf(in[idx]);
}

// fc_w [256 k][256 o] -> fcwT[o][k] bf16
__global__ __launch_bounds__(256) void fcwT_kernel(const float* __restrict__ in,
                                                   unsigned short* __restrict__ out) {
  int idx = blockIdx.x * 256 + threadIdx.x;   // idx = o*256 + k
  int o = idx >> 8, k = idx & 255;
  out[idx] = f2bf(in[k * 256 + o]);
}

// Bcat M1 part: Bcat[(n*32+d)*512 + k] = sum_c WQw[n][c][k] * Fw[n][c][d], k<256
// block per (n, ktile of 16); 256 threads
__global__ __launch_bounds__(256) void bcat_m1_kernel(const float* __restrict__ WQw,
                                                      const float* __restrict__ fcw,
                                                      unsigned short* __restrict__ Bcat) {
  __shared__ float wq_s[256][16];
  __shared__ float fw_s[256][32];
  int n = blockIdx.x >> 4, kt = blockIdx.x & 15;
  int t = threadIdx.x;
#pragma unroll
  for (int i = 0; i < 16; i++) {
    int c = i * 16 + (t >> 4), kk = t & 15;
    wq_s[c][kk] = WQw[(size_t)n * 65536 + c * 256 + kt * 16 + kk];
  }
#pragma unroll
  for (int i = 0; i < 32; i++) {
    int idx = i * 256 + t;             // c*32+d
    fw_s[idx >> 5][idx & 31] = fcw[(size_t)n * 24576 + idx];
  }
  __syncthreads();
  int kloc = t >> 4, dp = t & 15;
  float a0 = 0.f, a1v = 0.f;
  for (int c = 0; c < 256; c++) {
    float wv = wq_s[c][kloc];
    a0 = fmaf(wv, fw_s[c][dp * 2], a0);
    a1v = fmaf(wv, fw_s[c][dp * 2 + 1], a1v);
  }
  int k = kt * 16 + kloc;
  Bcat[((size_t)n * 32 + dp * 2) * 512 + k] = f2bf(a0);
  Bcat[((size_t)n * 32 + dp * 2 + 1) * 512 + k] = f2bf(a1v);
}

// Bcat data half: Bcat[(n*32+d)*512 + 256 + c] = Fw[n][256+2c][d]
__global__ __launch_bounds__(256) void bcat_m2_kernel(const float* __restrict__ fcw,
                                                      unsigned short* __restrict__ Bcat) {
  int idx = blockIdx.x * 256 + threadIdx.x;   // n*8192 + d*256 + c
  int n = idx >> 13, d = (idx >> 8) & 31, c = idx & 255;
  Bcat[((size_t)n * 32 + d) * 512 + 256 + c] =
      f2bf(fcw[((size_t)n * 768 + 256 + 2 * c) * 32 + d]);
}

// bqf[n][d] = sum_c WQb[n][c] * Fw[n][c][d]
__global__ __launch_bounds__(32) void bqf_kernel(const float* __restrict__ WQb,
                                                 const float* __restrict__ fcw,
                                                 float* __restrict__ bqf) {
  int n = blockIdx.x, d = threadIdx.x;
  float s = 0.f;
  for (int c = 0; c < 256; c++)
    s = fmaf(WQb[n * 256 + c], fcw[((size_t)n * 768 + c) * 32 + d], s);
  bqf[n * 32 + d] = s;
}

// w1[n][k] = sum_c a1[n][c]*WQw[n][c][k]; c1[n] = sum_c a1[n][c]*WQb[n][c]
__global__ __launch_bounds__(256) void w12_kernel(const float* __restrict__ WQw,
                                                  const float* __restrict__ WQb,
                                                  const float* __restrict__ a1,
                                                  const float* __restrict__ a2,
                                                  float* __restrict__ w1,
                                                  float* __restrict__ w2,
                                                  float* __restrict__ c1,
                                                  float* __restrict__ c2) {
  int n = blockIdx.x, t = threadIdx.x;
  float s1 = 0.f, s2 = 0.f;
  for (int c = 0; c < 256; c++) {
    float wv = WQw[((size_t)(n * 256 + c)) * 256 + t];
    s1 = fmaf(a1[n * 768 + c], wv, s1);
    s2 = fmaf(a2[n * 768 + c], wv, s2);
  }
  w1[n * 256 + t] = s1;
  w2[n * 256 + t] = s2;
  __shared__ float r1[256], r2[256];
  r1[t] = a1[n * 768 + t] * WQb[n * 256 + t];
  r2[t] = a2[n * 768 + t] * WQb[n * 256 + t];
  __syncthreads();
  for (int o = 128; o; o >>= 1) {
    if (t < o) { r1[t] += r1[t + o]; r2[t] += r2[t + o]; }
    __syncthreads();
  }
  if (t == 0) { c1[n] = r1[0]; c2[n] = r2[0]; }
}

// ---------------------------------------------------------------------------
__global__ __launch_bounds__(256) void ln_kernel(const float* __restrict__ nodes,
                                                 const float* __restrict__ g,
                                                 const float* __restrict__ bb,
                                                 float* __restrict__ xn,
                                                 unsigned short* __restrict__ xnb) {
  int row = blockIdx.x;
  int t = threadIdx.x;
  int lane = t & 63, w = t >> 6;
  __shared__ float red[4];
  float x = nodes[(size_t)row * HH + t];
  float s = x;
#pragma unroll
  for (int o = 32; o; o >>= 1) s += __shfl_xor(s, o);
  if (lane == 0) red[w] = s;
  __syncthreads();
  float mean = (red[0] + red[1] + red[2] + red[3]) * (1.0f / 256.0f);
  __syncthreads();
  float d = x - mean;
  float v = d * d;
#pragma unroll
  for (int o = 32; o; o >>= 1) v += __shfl_xor(v, o);
  if (lane == 0) red[w] = v;
  __syncthreads();
  float var = (red[0] + red[1] + red[2] + red[3]) * (1.0f / 256.0f);
  float rstd = rsqrtf(var + 1e-5f);
  float out = d * rstd * g[t] + bb[t];
  xn[(size_t)row * HH + t] = out;
  xnb[(size_t)row * HH + t] = f2bf(out);
}

__global__ __launch_bounds__(256) void rarf_kernel(const float* __restrict__ relay,
                                                   const float* __restrict__ a1,
                                                   const float* __restrict__ a2,
                                                   const float* __restrict__ fcw,
                                                   float* __restrict__ ra1,
                                                   float* __restrict__ ra2,
                                                   float* __restrict__ rf) {
  int n = blockIdx.x >> 4, b = blockIdx.x & 15;
  int t = threadIdx.x;
  int lane = t & 63, w = t >> 6;
  __shared__ float rel[256];
  __shared__ float red1[4], red2[4];
  __shared__ float pf_s[8][33];
  rel[t] = relay[b * HH + t];
  __syncthreads();
  float p1 = rel[t] * a1[n * 768 + 257 + 2 * t];
  float p2 = rel[t] * a2[n * 768 + 257 + 2 * t];
#pragma unroll
  for (int o = 32; o; o >>= 1) { p1 += __shfl_xor(p1, o); p2 += __shfl_xor(p2, o); }
  if (lane == 0) { red1[w] = p1; red2[w] = p2; }
  int d = t & 31, seg = t >> 5;
  float pf = 0.f;
  for (int u = 0; u < 32; u++) {
    int k = seg * 32 + u;
    pf = fmaf(rel[k], fcw[((size_t)n * 768 + 257 + 2 * k) * 32 + d], pf);
  }
  pf_s[seg][d] = pf;
  __syncthreads();
  if (t == 0) {
    ra1[n * 16 + b] = red1[0] + red1[1] + red1[2] + red1[3];
    ra2[n * 16 + b] = red2[0] + red2[1] + red2[2] + red2[3];
  }
  if (t < 32) {
    float s = 0.f;
    for (int gg = 0; gg < 8; gg++) s += pf_s[gg][t];
    rf[((size_t)n * 16 + b) * 32 + t] = s;
  }
}

// ei/ej: block = 4 rows (wave per row), loop all 8 heads; row read once
__global__ __launch_bounds__(256) void eiej3_kernel(const float* __restrict__ xn,
                                                    const float* __restrict__ data,
                                                    const float* __restrict__ w1,
                                                    const float* __restrict__ w2,
                                                    const float* __restrict__ a1,
                                                    const float* __restrict__ a2,
                                                    const float* __restrict__ c1,
                                                    const float* __restrict__ c2,
                                                    const float* __restrict__ ra1,
                                                    const float* __restrict__ ra2,
                                                    float* __restrict__ ei,
                                                    float* __restrict__ ej) {
  int r = blockIdx.x * 4 + (threadIdx.x >> 6);    // 0..8191 = b*512+l
  int b = r >> 9;
  int lane = threadIdx.x & 63;
  float xv[4], dv[4];
#pragma unroll
  for (int u = 0; u < 4; u++) {
    int c = lane + 64 * u;
    xv[u] = xn[(size_t)r * 256 + c];
    dv[u] = data[(size_t)r * 256 + c];
  }
  for (int n = 0; n < 8; n++) {
    float s1 = 0.f, s2 = 0.f;
#pragma unroll
    for (int u = 0; u < 4; u++) {
      int c = lane + 64 * u;
      s1 = fmaf(xv[u], w1[n * 256 + c], s1);
      s1 = fmaf(dv[u], a1[n * 768 + 256 + 2 * c], s1);
      s2 = fmaf(xv[u], w2[n * 256 + c], s2);
      s2 = fmaf(dv[u], a2[n * 768 + 256 + 2 * c], s2);
    }
#pragma unroll
    for (int o = 32; o; o >>= 1) { s1 += __shfl_xor(s1, o); s2 += __shfl_xor(s2, o); }
    if (lane == 0) {
      ei[n * 8192 + r] = s1 + c1[n] + ra1[n * 16 + b];
      ej[n * 8192 + r] = s2 + c2[n] + ra2[n * 16 + b];
    }
  }
}

// ---------------------------------------------------------------------------
// G-GEMM: GT[n][b][d][j] = [xn ; data](row j) @ Bcat col (n*32+d).  K=512 dual-A.
__global__ __launch_bounds__(256) void g_gemm_kernel(
    const unsigned short* __restrict__ A1, const unsigned short* __restrict__ A2,
    const unsigned short* __restrict__ Bcat, unsigned short* __restrict__ GT) {
  int tileN = blockIdx.x * 64;
  int tileM = blockIdx.y * 128;
  int t = threadIdx.x;
  int wv = t >> 6, lane = t & 63;
  int lo = lane & 15, quad = lane >> 4;
  int rowBase0 = tileM + wv * 32;
  const unsigned short* ap1[2];
  const unsigned short* ap2[2];
#pragma unroll
  for (int rt = 0; rt < 2; rt++) {
    int arow = rowBase0 + rt * 16 + lo;
    ap1[rt] = A1 + (size_t)arow * 256 + quad * 8;
    ap2[rt] = A2 + (size_t)arow * 256 + quad * 8;
  }
  f32x4 acc[2][4] = {};
  for (int k0 = 0; k0 < 512; k0 += 32) {
    bf16x8 af[2];
#pragma unroll
    for (int rt = 0; rt < 2; rt++)
      af[rt] = (k0 < 256) ? *(const bf16x8*)(ap1[rt] + k0)
                          : *(const bf16x8*)(ap2[rt] + k0 - 256);
#pragma unroll
    for (int ct = 0; ct < 4; ct++) {
      bf16x8 bf_ = *(const bf16x8*)(Bcat + (size_t)(tileN + ct * 16 + lo) * 512 + k0 + quad * 8);
#pragma unroll
      for (int rt = 0; rt < 2; rt++)
        acc[rt][ct] = __builtin_amdgcn_mfma_f32_16x16x32_bf16(af[rt], bf_, acc[rt][ct], 0, 0, 0);
    }
  }
#pragma unroll
  for (int rt = 0; rt < 2; rt++) {
#pragma unroll
    for (int ct = 0; ct < 4; ct++) {
      int co = tileN + ct * 16 + lo;
      int n = co >> 5, d = co & 31;
      int jrow = rowBase0 + rt * 16 + quad * 4;
      int b2 = jrow >> 9, jj = jrow & 511;
      ushort4 pk;
      pk.x = f2bf(acc[rt][ct][0]);
      pk.y = f2bf(acc[rt][ct][1]);
      pk.z = f2bf(acc[rt][ct][2]);
      pk.w = f2bf(acc[rt][ct][3]);
      *(ushort4*)&GT[(((size_t)(n * 16 + b2) * 32 + d) << 9) + jj] = pk;
    }
  }
}

// ---------------------------------------------------------------------------
// MFMA GEMM over K=256 bf16, M-tile 128, N-tile 64
// mode 1: fc epilogue; mode 2: plain fp32 out
__global__ __launch_bounds__(256) void mfma_gemm_kernel(
    const unsigned short* __restrict__ A, const unsigned short* __restrict__ Bw,
    const float* __restrict__ bias, int Mvalid, int mode,
    float* __restrict__ outF,
    const float* __restrict__ resid, const int* __restrict__ mask) {
  int tileN = blockIdx.x * 64;
  int tileM = blockIdx.y * 128;
  int t = threadIdx.x;
  int wv = t >> 6, lane = t & 63;
  int lo = lane & 15, quad = lane >> 4;
  int rowBase0 = tileM + wv * 32;
  const unsigned short* aptr[2];
#pragma unroll
  for (int rt = 0; rt < 2; rt++) {
    int arow = rowBase0 + rt * 16 + lo;
    if (arow >= Mvalid) arow = Mvalid - 1;
    aptr[rt] = A + (size_t)arow * 256 + quad * 8;
  }
  f32x4 acc[2][4] = {};
  for (int k0 = 0; k0 < 256; k0 += 32) {
    bf16x8 af[2];
#pragma unroll
    for (int rt = 0; rt < 2; rt++) af[rt] = *(const bf16x8*)(aptr[rt] + k0);
#pragma unroll
    for (int ct = 0; ct < 4; ct++) {
      bf16x8 bf_ = *(const bf16x8*)(Bw + (size_t)(tileN + ct * 16 + lo) * 256 + k0 + quad * 8);
#pragma unroll
      for (int rt = 0; rt < 2; rt++)
        acc[rt][ct] = __builtin_amdgcn_mfma_f32_16x16x32_bf16(af[rt], bf_, acc[rt][ct], 0, 0, 0);
    }
  }
#pragma unroll
  for (int rt = 0; rt < 2; rt++) {
    int rowBase = rowBase0 + rt * 16;
#pragma unroll
    for (int ct = 0; ct < 4; ct++) {
      int co = tileN + ct * 16 + lo;
      float bv = bias[co];
#pragma unroll
      for (int r = 0; r < 4; r++) {
        int row = rowBase + quad * 4 + r;
        if (row >= Mvalid) continue;
        float v = acc[rt][ct][r] + bv;
        if (mode == 1) {
          v = v > 0.f ? v : 0.01f * v;
          v = (mask[row] != 0) ? resid[(size_t)row * 256 + co] + v : 0.f;
        }
        outF[(size_t)row * 256 + co] = v;
      }
    }
  }
}

// ---------------------------------------------------------------------------
// GAT: softmax -> tiny MFMA aggregation vs pre-projected GT
// block: (n, b, 64 rows), 256 threads / 4 waves
__global__ __launch_bounds__(256) void gat_agg_kernel(
    const unsigned short* __restrict__ GT,    // [8][16][32][512] bf16
    const float* __restrict__ ei, const float* __restrict__ ej,
    const int* __restrict__ edge,
    const float* __restrict__ fcb, const float* __restrict__ rf,
    const float* __restrict__ bqf,
    unsigned short* __restrict__ tempb) {     // [8192][256] bf16
  __shared__ unsigned short W[64][512];       // 64KB, XOR-swizzled chunks
  int blk = blockIdx.x;
  int n = blk >> 7;
  int b = (blk >> 3) & 15;
  int i0 = (blk & 7) << 6;
  int t = threadIdx.x;
  int wv = t >> 6, lane = t & 63;
  int lo = lane & 15, quad = lane >> 4;

  // ---- Phase A: softmax rows wv*16 .. +15; store normalized bf16 swizzled
  const float* ejrow = ej + n * 8192 + b * 512;
  float ejv[8];
#pragma unroll
  for (int u = 0; u < 8; u++) ejv[u] = ejrow[lane + 64 * u];
  for (int rr = 0; rr < 16; rr++) {
    int row = wv * 16 + rr;
    float eiv = ei[n * 8192 + b * 512 + i0 + row];
    const int* adj = edge + (((size_t)b * 512 + i0 + row) << 9);
    float evv[8];
    float m = -3.0e38f;
#pragma unroll
    for (int u = 0; u < 8; u++) {
      int j = lane + 64 * u;
      float e;
      if (adj[j] > 0) { e = eiv + ejv[u]; e = e > 0.f ? e : 0.2f * e; }
      else e = -9.0e15f;
      evv[u] = e;
      m = fmaxf(m, e);
    }
#pragma unroll
    for (int o = 32; o; o >>= 1) m = fmaxf(m, __shfl_xor(m, o));
    float s = 0.f;
#pragma unroll
    for (int u = 0; u < 8; u++) {
      float wexp = __expf(evv[u] - m);
      evv[u] = wexp;
      s += wexp;
    }
#pragma unroll
    for (int o = 32; o; o >>= 1) s += __shfl_xor(s, o);
    float inv = 1.0f / s;
    int rx = (row & 7) << 3;
#pragma unroll
    for (int u = 0; u < 8; u++) {
      int col = lane + 64 * u;
      W[row][((col >> 3 << 3) ^ rx) + (col & 7)] = f2bf(evv[u] * inv);
    }
  }
  __syncthreads();

  // ---- Phase B: out[16 rows (this wave), 32 d] = W @ GT
  int arow = wv * 16 + lo;
  int rx = arow & 7;
  const unsigned short* gtb = GT + (((size_t)(n * 16 + b) * 32) << 9);
  f32x4 acc2[2] = {};
  for (int k0 = 0; k0 < 512; k0 += 32) {
    int chunk = (k0 >> 3) + quad;
    bf16x8 a0 = *(const bf16x8*)&W[arow][(chunk ^ rx) << 3];
#pragma unroll
    for (int ct = 0; ct < 2; ct++) {
      bf16x8 bf_ = *(const bf16x8*)(gtb + (((size_t)(ct * 16 + lo)) << 9) + k0 + quad * 8);
      acc2[ct] = __builtin_amdgcn_mfma_f32_16x16x32_bf16(a0, bf_, acc2[ct], 0, 0, 0);
    }
  }
#pragma unroll
  for (int ct = 0; ct < 2; ct++) {
    int d = ct * 16 + lo;
    float base = fcb[n * 32 + d] + rf[((size_t)n * 16 + b) * 32 + d] + bqf[n * 32 + d];
#pragma unroll
    for (int r = 0; r < 4; r++) {
      int row = wv * 16 + quad * 4 + r;
      float v = acc2[ct][r] + base;
      v = v > 0.f ? v : expm1f(v);
      tempb[((size_t)(b * 512 + i0 + row)) * 256 + n * 32 + d] = f2bf(v);
    }
  }
}

// ---------------------------------------------------------------------------
__global__ __launch_bounds__(256) void build_y_kernel(const float* __restrict__ relay,
                                                      const float* __restrict__ nodes,
                                                      unsigned short* __restrict__ yb) {
  int row = blockIdx.x;
  int b = row / LP1, l = row % LP1;
  const float* src = (l == 0) ? relay + (size_t)b * HH
                              : nodes + ((size_t)b * LL + l - 1) * HH;
  yb[(size_t)row * HH + threadIdx.x] = f2bf(src[threadIdx.x]);
}

__global__ __launch_bounds__(256) void small_gemm_kernel(const float* __restrict__ in,
                                                         const float* __restrict__ WT,
                                                         const float* __restrict__ bias,
                                                         float* __restrict__ out,
                                                         int act) {
  int row = blockIdx.x;
  int t = threadIdx.x;
  __shared__ float xr[256];
  xr[t] = in[(size_t)row * 256 + t];
  __syncthreads();
  float acc = 0.f;
  for (int k = 0; k < 256; k++) acc = fmaf(xr[k], WT[(size_t)k * 256 + t], acc);
  float v = acc + bias[t];
  if (act == 1) v = v > 0.f ? v : 0.01f * v;
  out[(size_t)row * 256 + t] = v;
}

__global__ __launch_bounds__(256) void star_attn_kernel(const float* __restrict__ qstar,
                                                        const float* __restrict__ kt,
                                                        const int* __restrict__ mask,
                                                        float* __restrict__ attstar) {
  int b = blockIdx.x >> 3, n = blockIdx.x & 7;
  int t = threadIdx.x;
  int lane = t & 63, w = t >> 6;
  __shared__ float qv[32];
  __shared__ float pre[LP1];
  __shared__ float red[4];
  __shared__ float par[8][33];
  if (t < 32) qv[t] = qstar[b * 256 + n * 32 + t];
  __syncthreads();
  const float scale = 0.17677669529663687f;
  for (int l = t; l < LP1; l += 256) {
    bool masked = (l > 0) && (mask[b * LL + l - 1] == 0);
    float p;
    if (masked) p = -3.4e38f;
    else {
      p = 0.f;
      const float* krow = kt + ((size_t)b * LP1 + l) * 256 + n * 32;
      for (int d = 0; d < 32; d++) p = fmaf(qv[d], krow[d], p);
      p *= scale;
    }
    pre[l] = p;
  }
  __syncthreads();
  float m = -3.4e38f;
  for (int l = t; l < LP1; l += 256) m = fmaxf(m, pre[l]);
#pragma unroll
  for (int o = 32; o; o >>= 1) m = fmaxf(m, __shfl_xor(m, o));
  if (lane == 0) red[w] = m;
  __syncthreads();
  m = fmaxf(fmaxf(red[0], red[1]), fmaxf(red[2], red[3]));
  __syncthreads();
  float s = 0.f;
  for (int l = t; l < LP1; l += 256) {
    float wv = __expf(pre[l] - m);
    pre[l] = wv;
    s += wv;
  }
#pragma unroll
  for (int o = 32; o; o >>= 1) s += __shfl_xor(s, o);
  if (lane == 0) red[w] = s;
  __syncthreads();
  float denom = red[0] + red[1] + red[2] + red[3];
  int d = t & 31, g = t >> 5;
  float acc = 0.f;
  for (int l = g; l < LP1; l += 8)
    acc = fmaf(pre[l], kt[((size_t)b * LP1 + l) * 256 + n * 32 + d], acc);
  par[g][d] = acc;
  __syncthreads();
  if (t < 32) {
    float a = 0.f;
    for (int gg = 0; gg < 8; gg++) a += par[gg][t];
    attstar[b * 256 + n * 32 + t] = a / denom;
  }
}

// ---------------------------------------------------------------------------
extern "C" void kernel_launch(void* const* d_in, const int* in_sizes, int n_in,
                              void* d_out, int out_size, void* d_ws, size_t ws_size,
                              hipStream_t stream) {
  const float* data  = (const float*)d_in[0];
  const float* WQw   = (const float*)d_in[1];
  const float* WQb   = (const float*)d_in[2];
  const float* a1    = (const float*)d_in[3];
  const float* a2    = (const float*)d_in[4];
  const float* fcw_g = (const float*)d_in[5];
  const float* fcb_g = (const float*)d_in[6];
  const float* ng    = (const float*)d_in[7];
  const float* nb    = (const float*)d_in[8];
  const float* sq_w  = (const float*)d_in[9];
  const float* sq_b  = (const float*)d_in[10];
  const float* sk_w  = (const float*)d_in[11];
  const float* sk_b  = (const float*)d_in[12];
  const float* so_w  = (const float*)d_in[13];
  const float* so_b  = (const float*)d_in[14];
  const float* fc_w  = (const float*)d_in[15];
  const float* fc_b  = (const float*)d_in[16];
  const int*   mask  = (const int*)d_in[17];
  const int*   edge  = (const int*)d_in[18];

  float* nodes = (float*)d_out;
  float* relay = nodes + NODES_ELEMS;

  char* p = (char*)d_ws;
  auto alloc = [&](size_t bytes) -> char* {
    char* r = p; p += (bytes + 255) & ~(size_t)255; return r;
  };
  float* xn            = (float*)alloc((size_t)8192 * 256 * 4);
  unsigned short* xnb  = (unsigned short*)alloc((size_t)8192 * 256 * 2);
  unsigned short* datab= (unsigned short*)alloc((size_t)8192 * 256 * 2);
  unsigned short* GT   = (unsigned short*)alloc((size_t)8 * 16 * 32 * 512 * 2);
  unsigned short* tmpb = (unsigned short*)alloc((size_t)8192 * 256 * 2);
  unsigned short* yb   = (unsigned short*)alloc((size_t)8208 * 256 * 2);
  float* kt            = (float*)alloc((size_t)8208 * 256 * 4);
  float* ei            = (float*)alloc(65536 * 4);
  float* ej            = (float*)alloc(65536 * 4);
  float* ra1           = (float*)alloc(128 * 4);
  float* ra2           = (float*)alloc(128 * 4);
  float* rf            = (float*)alloc(4096 * 4);
  float* bqf           = (float*)alloc(256 * 4);
  float* w1            = (float*)alloc(2048 * 4);
  float* w2            = (float*)alloc(2048 * 4);
  float* c1            = (float*)alloc(8 * 4);
  float* c2            = (float*)alloc(8 * 4);
  unsigned short* Bcat = (unsigned short*)alloc((size_t)256 * 512 * 2);
  unsigned short* fcwT = (unsigned short*)alloc((size_t)65536 * 2);
  unsigned short* skwb = (unsigned short*)alloc((size_t)131072 * 2);
  float* sqT           = (float*)alloc((size_t)131072 * 4);
  float* soT           = (float*)alloc((size_t)131072 * 4);
  float* qst           = (float*)alloc(4096 * 4);
  float* atts          = (float*)alloc(4096 * 4);

  hipMemcpyAsync(nodes, data, (size_t)NODES_ELEMS * sizeof(float),
                 hipMemcpyDeviceToDevice, stream);
  init_relay_kernel<<<BB, 256, 0, stream>>>(data, relay);

  // one-time precomputes
  w12_kernel<<<8, 256, 0, stream>>>(WQw, WQb, a1, a2, w1, w2, c1, c2);
  bcat_m1_kernel<<<128, 256, 0, stream>>>(WQw, fcw_g, Bcat);
  bcat_m2_kernel<<<256, 256, 0, stream>>>(fcw_g, Bcat);
  bqf_kernel<<<8, 32, 0, stream>>>(WQb, fcw_g, bqf);
  fcwT_kernel<<<256, 256, 0, stream>>>(fc_w, fcwT);
  cvt_bf16_kernel<<<512, 256, 0, stream>>>(sk_w, skwb, 131072);
  cvt_bf16_kernel<<<8192, 256, 0, stream>>>(data, datab, 8192 * 256);
  for (int it = 0; it < 2; it++) {
    transpose_kernel<<<256, 256, 0, stream>>>(sq_w + it * 65536, sqT + it * 65536, 256, 256);
    transpose_kernel<<<256, 256, 0, stream>>>(so_w + it * 65536, soT + it * 65536, 256, 256);
  }

  for (int it = 0; it < 2; it++) {
    ln_kernel<<<BB * LL, 256, 0, stream>>>(nodes, ng + it * 256, nb + it * 256, xn, xnb);
    rarf_kernel<<<NHEAD * BB, 256, 0, stream>>>(relay, a1, a2, fcw_g, ra1, ra2, rf);
    eiej3_kernel<<<2048, 256, 0, stream>>>(xn, data, w1, w2, a1, a2,
                                           c1, c2, ra1, ra2, ei, ej);
    // GT = [xn;data] @ Bcat  (pre-projected per-head GAT values)
    g_gemm_kernel<<<dim3(4, 64), 256, 0, stream>>>(xnb, datab, Bcat, GT);
    gat_agg_kernel<<<NHEAD * BB * 8, 256, 0, stream>>>(GT, ei, ej, edge,
                                                       fcb_g, rf, bqf, tmpb);
    // nodes = mask ? nodes + lrelu(temp @ fc_w + fc_b) : 0
    mfma_gemm_kernel<<<dim3(4, 64), 256, 0, stream>>>(tmpb, fcwT, fc_b, 8192, 1,
                                                      nodes, nodes, mask);
    build_y_kernel<<<BB * LP1, 256, 0, stream>>>(relay, nodes, yb);
    // kt = y @ sk_wT + sk_b
    mfma_gemm_kernel<<<dim3(4, 65), 256, 0, stream>>>(yb, skwb + it * 65536,
                                                      sk_b + it * 256, 8208, 2,
                                                      kt, nullptr, nullptr);
    small_gemm_kernel<<<BB, 256, 0, stream>>>(relay, sqT + it * 65536, sq_b + it * 256,
                                              qst, 0);
    star_attn_kernel<<<BB * NHEAD, 256, 0, stream>>>(qst, kt, mask, atts);
    small_gemm_kernel<<<BB, 256, 0, stream>>>(atts, soT + it * 65536, so_b + it * 256,
                                              relay, 1);
  }
}

// Round 5
// 483.007 us; speedup vs baseline: 4.4172x; 1.0711x over previous
//
#include <hip/hip_runtime.h>
#include <hip/hip_bf16.h>
#include <math.h>

#define BB 16
#define LL 512
#define HH 256
#define NHEAD 8
#define HDIM 32
#define LP1 513
#define NHHD 256
#define NODES_ELEMS (BB*LL*HH)

typedef __attribute__((ext_vector_type(8))) short bf16x8;
typedef __attribute__((ext_vector_type(4))) float f32x4;

__device__ __forceinline__ unsigned short f2bf(float f) {
  union { float f; unsigned u; } x; x.f = f;
  unsigned r = x.u + 0x7fffu + ((x.u >> 16) & 1u);
  return (unsigned short)(r >> 16);
}

// ---------------------------------------------------------------------------
__global__ __launch_bounds__(256) void init_relay_kernel(const float* __restrict__ data,
                                                         float* __restrict__ relay) {
  int b = blockIdx.x, t = threadIdx.x;
  float s = 0.f;
  const float* p = data + (size_t)b * LL * HH + t;
  for (int l = 0; l < LL; l++) s += p[(size_t)l * HH];
  relay[b * HH + t] = s * (1.0f / 512.0f);
}

__global__ __launch_bounds__(256) void transpose_kernel(const float* __restrict__ in,
                                                        float* __restrict__ out,
                                                        int R, int C) {
  int idx = blockIdx.x * 256 + threadIdx.x;
  if (idx < R * C) {
    int r = idx / C, c = idx % C;
    out[(size_t)c * R + r] = in[idx];
  }
}

__global__ __launch_bounds__(256) void cvt_bf16_kernel(const float* __restrict__ in,
                                                       unsigned short* __restrict__ out,
                                                       int n) {
  int idx = blockIdx.x * 256 + threadIdx.x;
  if (idx < n) out[idx] = f2bf(in[idx]);
}

// edge -> packed bits: ep[row*64+lane] bit u = edge[row][lane+64u] > 0
__global__ __launch_bounds__(256) void edge_pack_kernel(const int* __restrict__ edge,
                                                        unsigned char* __restrict__ ep) {
  int row = blockIdx.x * 4 + (threadIdx.x >> 6);  // 0..8191 (b*512+i)
  int lane = threadIdx.x & 63;
  const int* adj = edge + ((size_t)row << 9);
  unsigned v = 0;
#pragma unroll
  for (int u = 0; u < 8; u++) v |= (adj[lane + 64 * u] > 0 ? 1u : 0u) << u;
  ep[((size_t)row << 6) + lane] = (unsigned char)v;
}

// fc_w [256 k][256 o] -> fcwT[o][k] bf16
__global__ __launch_bounds__(256) void fcwT_kernel(const float* __restrict__ in,
                                                   unsigned short* __restrict__ out) {
  int idx = blockIdx.x * 256 + threadIdx.x;   // idx = o*256 + k
  int o = idx >> 8, k = idx & 255;
  out[idx] = f2bf(in[k * 256 + o]);
}

// Bcat M1 part: Bcat[(n*32+d)*512 + k] = sum_c WQw[n][c][k] * Fw[n][c][d], k<256
__global__ __launch_bounds__(256) void bcat_m1_kernel(const float* __restrict__ WQw,
                                                      const float* __restrict__ fcw,
                                                      unsigned short* __restrict__ Bcat) {
  __shared__ float wq_s[256][16];
  __shared__ float fw_s[256][32];
  int n = blockIdx.x >> 4, kt = blockIdx.x & 15;
  int t = threadIdx.x;
#pragma unroll
  for (int i = 0; i < 16; i++) {
    int c = i * 16 + (t >> 4), kk = t & 15;
    wq_s[c][kk] = WQw[(size_t)n * 65536 + c * 256 + kt * 16 + kk];
  }
#pragma unroll
  for (int i = 0; i < 32; i++) {
    int idx = i * 256 + t;             // c*32+d
    fw_s[idx >> 5][idx & 31] = fcw[(size_t)n * 24576 + idx];
  }
  __syncthreads();
  int kloc = t >> 4, dp = t & 15;
  float a0 = 0.f, a1v = 0.f;
  for (int c = 0; c < 256; c++) {
    float wv = wq_s[c][kloc];
    a0 = fmaf(wv, fw_s[c][dp * 2], a0);
    a1v = fmaf(wv, fw_s[c][dp * 2 + 1], a1v);
  }
  int k = kt * 16 + kloc;
  Bcat[((size_t)n * 32 + dp * 2) * 512 + k] = f2bf(a0);
  Bcat[((size_t)n * 32 + dp * 2 + 1) * 512 + k] = f2bf(a1v);
}

// Bcat data half: Bcat[(n*32+d)*512 + 256 + c] = Fw[n][256+2c][d]
__global__ __launch_bounds__(256) void bcat_m2_kernel(const float* __restrict__ fcw,
                                                      unsigned short* __restrict__ Bcat) {
  int idx = blockIdx.x * 256 + threadIdx.x;   // n*8192 + d*256 + c
  int n = idx >> 13, d = (idx >> 8) & 31, c = idx & 255;
  Bcat[((size_t)n * 32 + d) * 512 + 256 + c] =
      f2bf(fcw[((size_t)n * 768 + 256 + 2 * c) * 32 + d]);
}

// bqf[n][d] = sum_c WQb[n][c] * Fw[n][c][d]
__global__ __launch_bounds__(32) void bqf_kernel(const float* __restrict__ WQb,
                                                 const float* __restrict__ fcw,
                                                 float* __restrict__ bqf) {
  int n = blockIdx.x, d = threadIdx.x;
  float s = 0.f;
  for (int c = 0; c < 256; c++)
    s = fmaf(WQb[n * 256 + c], fcw[((size_t)n * 768 + c) * 32 + d], s);
  bqf[n * 32 + d] = s;
}

// w1[n][k] = sum_c a1[n][c]*WQw[n][c][k]; c1[n] = sum_c a1[n][c]*WQb[n][c]
__global__ __launch_bounds__(256) void w12_kernel(const float* __restrict__ WQw,
                                                  const float* __restrict__ WQb,
                                                  const float* __restrict__ a1,
                                                  const float* __restrict__ a2,
                                                  float* __restrict__ w1,
                                                  float* __restrict__ w2,
                                                  float* __restrict__ c1,
                                                  float* __restrict__ c2) {
  int n = blockIdx.x, t = threadIdx.x;
  float s1 = 0.f, s2 = 0.f;
  for (int c = 0; c < 256; c++) {
    float wv = WQw[((size_t)(n * 256 + c)) * 256 + t];
    s1 = fmaf(a1[n * 768 + c], wv, s1);
    s2 = fmaf(a2[n * 768 + c], wv, s2);
  }
  w1[n * 256 + t] = s1;
  w2[n * 256 + t] = s2;
  __shared__ float r1[256], r2[256];
  r1[t] = a1[n * 768 + t] * WQb[n * 256 + t];
  r2[t] = a2[n * 768 + t] * WQb[n * 256 + t];
  __syncthreads();
  for (int o = 128; o; o >>= 1) {
    if (t < o) { r1[t] += r1[t + o]; r2[t] += r2[t + o]; }
    __syncthreads();
  }
  if (t == 0) { c1[n] = r1[0]; c2[n] = r2[0]; }
}

// ---------------------------------------------------------------------------
// rarf: also folds fcb + bqf into rf  => rf = rf_relay + fcb + bqf
__global__ __launch_bounds__(256) void rarf_kernel(const float* __restrict__ relay,
                                                   const float* __restrict__ a1,
                                                   const float* __restrict__ a2,
                                                   const float* __restrict__ fcw,
                                                   const float* __restrict__ fcb,
                                                   const float* __restrict__ bqf,
                                                   float* __restrict__ ra1,
                                                   float* __restrict__ ra2,
                                                   float* __restrict__ rf) {
  int n = blockIdx.x >> 4, b = blockIdx.x & 15;
  int t = threadIdx.x;
  int lane = t & 63, w = t >> 6;
  __shared__ float rel[256];
  __shared__ float red1[4], red2[4];
  __shared__ float pf_s[8][33];
  rel[t] = relay[b * HH + t];
  __syncthreads();
  float p1 = rel[t] * a1[n * 768 + 257 + 2 * t];
  float p2 = rel[t] * a2[n * 768 + 257 + 2 * t];
#pragma unroll
  for (int o = 32; o; o >>= 1) { p1 += __shfl_xor(p1, o); p2 += __shfl_xor(p2, o); }
  if (lane == 0) { red1[w] = p1; red2[w] = p2; }
  int d = t & 31, seg = t >> 5;
  float pf = 0.f;
  for (int u = 0; u < 32; u++) {
    int k = seg * 32 + u;
    pf = fmaf(rel[k], fcw[((size_t)n * 768 + 257 + 2 * k) * 32 + d], pf);
  }
  pf_s[seg][d] = pf;
  __syncthreads();
  if (t == 0) {
    ra1[n * 16 + b] = red1[0] + red1[1] + red1[2] + red1[3];
    ra2[n * 16 + b] = red2[0] + red2[1] + red2[2] + red2[3];
  }
  if (t < 32) {
    float s = 0.f;
    for (int gg = 0; gg < 8; gg++) s += pf_s[gg][t];
    rf[((size_t)n * 16 + b) * 32 + t] = s + fcb[n * 32 + t] + bqf[n * 32 + t];
  }
}

// ---------------------------------------------------------------------------
// Fused LayerNorm + ei/ej: one wave per row; writes xnb bf16 + ei/ej all heads
__global__ __launch_bounds__(256) void lnei_kernel(const float* __restrict__ nodes,
                                                   const float* __restrict__ data,
                                                   const float* __restrict__ g,
                                                   const float* __restrict__ bb,
                                                   const float* __restrict__ w1,
                                                   const float* __restrict__ w2,
                                                   const float* __restrict__ a1,
                                                   const float* __restrict__ a2,
                                                   const float* __restrict__ c1,
                                                   const float* __restrict__ c2,
                                                   const float* __restrict__ ra1,
                                                   const float* __restrict__ ra2,
                                                   unsigned short* __restrict__ xnb,
                                                   float* __restrict__ ei,
                                                   float* __restrict__ ej) {
  int r = blockIdx.x * 4 + (threadIdx.x >> 6);    // b*512+l
  int b = r >> 9;
  int lane = threadIdx.x & 63;
  float x[4], dv[4];
#pragma unroll
  for (int u = 0; u < 4; u++) {
    int c = lane + 64 * u;
    x[u] = nodes[(size_t)r * 256 + c];
    dv[u] = data[(size_t)r * 256 + c];
  }
  float s = x[0] + x[1] + x[2] + x[3];
#pragma unroll
  for (int o = 32; o; o >>= 1) s += __shfl_xor(s, o);
  float mean = s * (1.0f / 256.0f);
  float v = 0.f;
#pragma unroll
  for (int u = 0; u < 4; u++) { x[u] -= mean; v = fmaf(x[u], x[u], v); }
#pragma unroll
  for (int o = 32; o; o >>= 1) v += __shfl_xor(v, o);
  float rstd = rsqrtf(v * (1.0f / 256.0f) + 1e-5f);
  float xv[4];
#pragma unroll
  for (int u = 0; u < 4; u++) {
    int c = lane + 64 * u;
    xv[u] = x[u] * rstd * g[c] + bb[c];
    xnb[(size_t)r * 256 + c] = f2bf(xv[u]);
  }
  for (int n = 0; n < 8; n++) {
    float s1 = 0.f, s2 = 0.f;
#pragma unroll
    for (int u = 0; u < 4; u++) {
      int c = lane + 64 * u;
      s1 = fmaf(xv[u], w1[n * 256 + c], s1);
      s1 = fmaf(dv[u], a1[n * 768 + 256 + 2 * c], s1);
      s2 = fmaf(xv[u], w2[n * 256 + c], s2);
      s2 = fmaf(dv[u], a2[n * 768 + 256 + 2 * c], s2);
    }
#pragma unroll
    for (int o = 32; o; o >>= 1) { s1 += __shfl_xor(s1, o); s2 += __shfl_xor(s2, o); }
    if (lane == 0) {
      ei[n * 8192 + r] = s1 + c1[n] + ra1[n * 16 + b];
      ej[n * 8192 + r] = s2 + c2[n] + ra2[n * 16 + b];
    }
  }
}

// ---------------------------------------------------------------------------
// G-GEMM: GT[n][b][d][j] = [xn ; data](row j) @ Bcat col (n*32+d).  K=512 dual-A.
__global__ __launch_bounds__(256) void g_gemm_kernel(
    const unsigned short* __restrict__ A1, const unsigned short* __restrict__ A2,
    const unsigned short* __restrict__ Bcat, unsigned short* __restrict__ GT) {
  int tileN = blockIdx.x * 64;
  int tileM = blockIdx.y * 128;
  int t = threadIdx.x;
  int wv = t >> 6, lane = t & 63;
  int lo = lane & 15, quad = lane >> 4;
  int rowBase0 = tileM + wv * 32;
  const unsigned short* ap1[2];
  const unsigned short* ap2[2];
#pragma unroll
  for (int rt = 0; rt < 2; rt++) {
    int arow = rowBase0 + rt * 16 + lo;
    ap1[rt] = A1 + (size_t)arow * 256 + quad * 8;
    ap2[rt] = A2 + (size_t)arow * 256 + quad * 8;
  }
  f32x4 acc[2][4] = {};
  for (int k0 = 0; k0 < 512; k0 += 32) {
    bf16x8 af[2];
#pragma unroll
    for (int rt = 0; rt < 2; rt++)
      af[rt] = (k0 < 256) ? *(const bf16x8*)(ap1[rt] + k0)
                          : *(const bf16x8*)(ap2[rt] + k0 - 256);
#pragma unroll
    for (int ct = 0; ct < 4; ct++) {
      bf16x8 bf_ = *(const bf16x8*)(Bcat + (size_t)(tileN + ct * 16 + lo) * 512 + k0 + quad * 8);
#pragma unroll
      for (int rt = 0; rt < 2; rt++)
        acc[rt][ct] = __builtin_amdgcn_mfma_f32_16x16x32_bf16(af[rt], bf_, acc[rt][ct], 0, 0, 0);
    }
  }
#pragma unroll
  for (int rt = 0; rt < 2; rt++) {
#pragma unroll
    for (int ct = 0; ct < 4; ct++) {
      int co = tileN + ct * 16 + lo;
      int n = co >> 5, d = co & 31;
      int jrow = rowBase0 + rt * 16 + quad * 4;
      int b2 = jrow >> 9, jj = jrow & 511;
      ushort4 pk;
      pk.x = f2bf(acc[rt][ct][0]);
      pk.y = f2bf(acc[rt][ct][1]);
      pk.z = f2bf(acc[rt][ct][2]);
      pk.w = f2bf(acc[rt][ct][3]);
      *(ushort4*)&GT[(((size_t)(n * 16 + b2) * 32 + d) << 9) + jj] = pk;
    }
  }
}

// ---------------------------------------------------------------------------
// MFMA GEMM over K=256 bf16, M-tile 128, N-tile 64
// mode 1: fc epilogue; mode 2: plain fp32 out
__global__ __launch_bounds__(256) void mfma_gemm_kernel(
    const unsigned short* __restrict__ A, const unsigned short* __restrict__ Bw,
    const float* __restrict__ bias, int Mvalid, int mode,
    float* __restrict__ outF,
    const float* __restrict__ resid, const int* __restrict__ mask) {
  int tileN = blockIdx.x * 64;
  int tileM = blockIdx.y * 128;
  int t = threadIdx.x;
  int wv = t >> 6, lane = t & 63;
  int lo = lane & 15, quad = lane >> 4;
  int rowBase0 = tileM + wv * 32;
  const unsigned short* aptr[2];
#pragma unroll
  for (int rt = 0; rt < 2; rt++) {
    int arow = rowBase0 + rt * 16 + lo;
    if (arow >= Mvalid) arow = Mvalid - 1;
    aptr[rt] = A + (size_t)arow * 256 + quad * 8;
  }
  f32x4 acc[2][4] = {};
  for (int k0 = 0; k0 < 256; k0 += 32) {
    bf16x8 af[2];
#pragma unroll
    for (int rt = 0; rt < 2; rt++) af[rt] = *(const bf16x8*)(aptr[rt] + k0);
#pragma unroll
    for (int ct = 0; ct < 4; ct++) {
      bf16x8 bf_ = *(const bf16x8*)(Bw + (size_t)(tileN + ct * 16 + lo) * 256 + k0 + quad * 8);
#pragma unroll
      for (int rt = 0; rt < 2; rt++)
        acc[rt][ct] = __builtin_amdgcn_mfma_f32_16x16x32_bf16(af[rt], bf_, acc[rt][ct], 0, 0, 0);
    }
  }
#pragma unroll
  for (int rt = 0; rt < 2; rt++) {
    int rowBase = rowBase0 + rt * 16;
#pragma unroll
    for (int ct = 0; ct < 4; ct++) {
      int co = tileN + ct * 16 + lo;
      float bv = bias[co];
#pragma unroll
      for (int r = 0; r < 4; r++) {
        int row = rowBase + quad * 4 + r;
        if (row >= Mvalid) continue;
        float v = acc[rt][ct][r] + bv;
        if (mode == 1) {
          v = v > 0.f ? v : 0.01f * v;
          v = (mask[row] != 0) ? resid[(size_t)row * 256 + co] + v : 0.f;
        }
        outF[(size_t)row * 256 + co] = v;
      }
    }
  }
}

// ---------------------------------------------------------------------------
// GAT: softmax (packed-edge) -> tiny MFMA aggregation vs pre-projected GT
// block: (n, b, 32 rows), 256 threads / 4 waves; wave = 8 softmax rows,
// then (row-tile, d-half) split for the MFMA.
__global__ __launch_bounds__(256) void gat_agg_kernel(
    const unsigned short* __restrict__ GT,    // [8][16][32][512] bf16
    const float* __restrict__ ei, const float* __restrict__ ej,
    const unsigned char* __restrict__ ep,     // [8192][64] packed adj bits
    const float* __restrict__ rf,             // rf + fcb + bqf folded
    unsigned short* __restrict__ tempb) {     // [8192][256] bf16
  __shared__ unsigned short W[32][512];       // 32KB, XOR-swizzled chunks
  int blk = blockIdx.x;
  int n = blk >> 8;
  int b = (blk >> 4) & 15;
  int i0 = (blk & 15) << 5;
  int t = threadIdx.x;
  int wv = t >> 6, lane = t & 63;
  int lo = lane & 15, quad = lane >> 4;

  // ---- Phase A: softmax rows wv*8 .. +7; store normalized bf16 swizzled
  const float* ejrow = ej + n * 8192 + b * 512;
  float ejv[8];
#pragma unroll
  for (int u = 0; u < 8; u++) ejv[u] = ejrow[lane + 64 * u];
  for (int rr = 0; rr < 8; rr++) {
    int row = wv * 8 + rr;
    float eiv = ei[n * 8192 + b * 512 + i0 + row];
    unsigned pb = ep[(((size_t)(b * 512 + i0 + row)) << 6) + lane];
    float evv[8];
    float m = -3.0e38f;
#pragma unroll
    for (int u = 0; u < 8; u++) {
      float e;
      if ((pb >> u) & 1) { e = eiv + ejv[u]; e = e > 0.f ? e : 0.2f * e; }
      else e = -9.0e15f;
      evv[u] = e;
      m = fmaxf(m, e);
    }
#pragma unroll
    for (int o = 32; o; o >>= 1) m = fmaxf(m, __shfl_xor(m, o));
    float s = 0.f;
#pragma unroll
    for (int u = 0; u < 8; u++) {
      float wexp = __expf(evv[u] - m);
      evv[u] = wexp;
      s += wexp;
    }
#pragma unroll
    for (int o = 32; o; o >>= 1) s += __shfl_xor(s, o);
    float inv = 1.0f / s;
    int rx = (row & 7) << 3;
#pragma unroll
    for (int u = 0; u < 8; u++) {
      int col = lane + 64 * u;
      W[row][((col >> 3 << 3) ^ rx) + (col & 7)] = f2bf(evv[u] * inv);
    }
  }
  __syncthreads();

  // ---- Phase B: wave (rt, dh): rows rt*16..+15, d = dh*16..+15
  int rt = wv >> 1, dh = wv & 1;
  int arow = rt * 16 + lo;
  int rx = arow & 7;
  const unsigned short* gtb = GT + (((size_t)(n * 16 + b) * 32) << 9);
  f32x4 acc = {};
  for (int k0 = 0; k0 < 512; k0 += 32) {
    int chunk = (k0 >> 3) + quad;
    bf16x8 a0 = *(const bf16x8*)&W[arow][(chunk ^ rx) << 3];
    bf16x8 bf_ = *(const bf16x8*)(gtb + (((size_t)(dh * 16 + lo)) << 9) + k0 + quad * 8);
    acc = __builtin_amdgcn_mfma_f32_16x16x32_bf16(a0, bf_, acc, 0, 0, 0);
  }
  int d = dh * 16 + lo;
  float base = rf[((size_t)n * 16 + b) * 32 + d];
#pragma unroll
  for (int r = 0; r < 4; r++) {
    int row = rt * 16 + quad * 4 + r;
    float v = acc[r] + base;
    v = v > 0.f ? v : expm1f(v);
    tempb[((size_t)(b * 512 + i0 + row)) * 256 + n * 32 + d] = f2bf(v);
  }
}

// ---------------------------------------------------------------------------
__global__ __launch_bounds__(256) void build_y_kernel(const float* __restrict__ relay,
                                                      const float* __restrict__ nodes,
                                                      unsigned short* __restrict__ yb) {
  int row = blockIdx.x;
  int b = row / LP1, l = row % LP1;
  const float* src = (l == 0) ? relay + (size_t)b * HH
                              : nodes + ((size_t)b * LL + l - 1) * HH;
  yb[(size_t)row * HH + threadIdx.x] = f2bf(src[threadIdx.x]);
}

__global__ __launch_bounds__(256) void small_gemm_kernel(const float* __restrict__ in,
                                                         const float* __restrict__ WT,
                                                         const float* __restrict__ bias,
                                                         float* __restrict__ out,
                                                         int act) {
  int row = blockIdx.x;
  int t = threadIdx.x;
  __shared__ float xr[256];
  xr[t] = in[(size_t)row * 256 + t];
  __syncthreads();
  float acc = 0.f;
  for (int k = 0; k < 256; k++) acc = fmaf(xr[k], WT[(size_t)k * 256 + t], acc);
  float v = acc + bias[t];
  if (act == 1) v = v > 0.f ? v : 0.01f * v;
  out[(size_t)row * 256 + t] = v;
}

__global__ __launch_bounds__(256) void star_attn_kernel(const float* __restrict__ qstar,
                                                        const float* __restrict__ kt,
                                                        const int* __restrict__ mask,
                                                        float* __restrict__ attstar) {
  int b = blockIdx.x >> 3, n = blockIdx.x & 7;
  int t = threadIdx.x;
  int lane = t & 63, w = t >> 6;
  __shared__ float qv[32];
  __shared__ float pre[LP1];
  __shared__ float red[4];
  __shared__ float par[8][33];
  if (t < 32) qv[t] = qstar[b * 256 + n * 32 + t];
  __syncthreads();
  const float scale = 0.17677669529663687f;
  for (int l = t; l < LP1; l += 256) {
    bool masked = (l > 0) && (mask[b * LL + l - 1] == 0);
    float p;
    if (masked) p = -3.4e38f;
    else {
      p = 0.f;
      const float* krow = kt + ((size_t)b * LP1 + l) * 256 + n * 32;
      for (int d = 0; d < 32; d++) p = fmaf(qv[d], krow[d], p);
      p *= scale;
    }
    pre[l] = p;
  }
  __syncthreads();
  float m = -3.4e38f;
  for (int l = t; l < LP1; l += 256) m = fmaxf(m, pre[l]);
#pragma unroll
  for (int o = 32; o; o >>= 1) m = fmaxf(m, __shfl_xor(m, o));
  if (lane == 0) red[w] = m;
  __syncthreads();
  m = fmaxf(fmaxf(red[0], red[1]), fmaxf(red[2], red[3]));
  __syncthreads();
  float s = 0.f;
  for (int l = t; l < LP1; l += 256) {
    float wv = __expf(pre[l] - m);
    pre[l] = wv;
    s += wv;
  }
#pragma unroll
  for (int o = 32; o; o >>= 1) s += __shfl_xor(s, o);
  if (lane == 0) red[w] = s;
  __syncthreads();
  float denom = red[0] + red[1] + red[2] + red[3];
  int d = t & 31, g = t >> 5;
  float acc = 0.f;
  for (int l = g; l < LP1; l += 8)
    acc = fmaf(pre[l], kt[((size_t)b * LP1 + l) * 256 + n * 32 + d], acc);
  par[g][d] = acc;
  __syncthreads();
  if (t < 32) {
    float a = 0.f;
    for (int gg = 0; gg < 8; gg++) a += par[gg][t];
    attstar[b * 256 + n * 32 + t] = a / denom;
  }
}

// ---------------------------------------------------------------------------
extern "C" void kernel_launch(void* const* d_in, const int* in_sizes, int n_in,
                              void* d_out, int out_size, void* d_ws, size_t ws_size,
                              hipStream_t stream) {
  const float* data  = (const float*)d_in[0];
  const float* WQw   = (const float*)d_in[1];
  const float* WQb   = (const float*)d_in[2];
  const float* a1    = (const float*)d_in[3];
  const float* a2    = (const float*)d_in[4];
  const float* fcw_g = (const float*)d_in[5];
  const float* fcb_g = (const float*)d_in[6];
  const float* ng    = (const float*)d_in[7];
  const float* nb    = (const float*)d_in[8];
  const float* sq_w  = (const float*)d_in[9];
  const float* sq_b  = (const float*)d_in[10];
  const float* sk_w  = (const float*)d_in[11];
  const float* sk_b  = (const float*)d_in[12];
  const float* so_w  = (const float*)d_in[13];
  const float* so_b  = (const float*)d_in[14];
  const float* fc_w  = (const float*)d_in[15];
  const float* fc_b  = (const float*)d_in[16];
  const int*   mask  = (const int*)d_in[17];
  const int*   edge  = (const int*)d_in[18];

  float* nodes = (float*)d_out;
  float* relay = nodes + NODES_ELEMS;

  char* p = (char*)d_ws;
  auto alloc = [&](size_t bytes) -> char* {
    char* r = p; p += (bytes + 255) & ~(size_t)255; return r;
  };
  unsigned short* xnb  = (unsigned short*)alloc((size_t)8192 * 256 * 2);
  unsigned short* datab= (unsigned short*)alloc((size_t)8192 * 256 * 2);
  unsigned short* GT   = (unsigned short*)alloc((size_t)8 * 16 * 32 * 512 * 2);
  unsigned short* tmpb = (unsigned short*)alloc((size_t)8192 * 256 * 2);
  unsigned short* yb   = (unsigned short*)alloc((size_t)8208 * 256 * 2);
  float* kt            = (float*)alloc((size_t)8208 * 256 * 4);
  unsigned char* ep    = (unsigned char*)alloc((size_t)8192 * 64);
  float* ei            = (float*)alloc(65536 * 4);
  float* ej            = (float*)alloc(65536 * 4);
  float* ra1           = (float*)alloc(128 * 4);
  float* ra2           = (float*)alloc(128 * 4);
  float* rf            = (float*)alloc(4096 * 4);
  float* bqf           = (float*)alloc(256 * 4);
  float* w1            = (float*)alloc(2048 * 4);
  float* w2            = (float*)alloc(2048 * 4);
  float* c1            = (float*)alloc(8 * 4);
  float* c2            = (float*)alloc(8 * 4);
  unsigned short* Bcat = (unsigned short*)alloc((size_t)256 * 512 * 2);
  unsigned short* fcwT = (unsigned short*)alloc((size_t)65536 * 2);
  unsigned short* skwb = (unsigned short*)alloc((size_t)131072 * 2);
  float* sqT           = (float*)alloc((size_t)131072 * 4);
  float* soT           = (float*)alloc((size_t)131072 * 4);
  float* qst           = (float*)alloc(4096 * 4);
  float* atts          = (float*)alloc(4096 * 4);

  hipMemcpyAsync(nodes, data, (size_t)NODES_ELEMS * sizeof(float),
                 hipMemcpyDeviceToDevice, stream);
  init_relay_kernel<<<BB, 256, 0, stream>>>(data, relay);

  // one-time precomputes
  w12_kernel<<<8, 256, 0, stream>>>(WQw, WQb, a1, a2, w1, w2, c1, c2);
  bcat_m1_kernel<<<128, 256, 0, stream>>>(WQw, fcw_g, Bcat);
  bcat_m2_kernel<<<256, 256, 0, stream>>>(fcw_g, Bcat);
  bqf_kernel<<<8, 32, 0, stream>>>(WQb, fcw_g, bqf);
  fcwT_kernel<<<256, 256, 0, stream>>>(fc_w, fcwT);
  cvt_bf16_kernel<<<512, 256, 0, stream>>>(sk_w, skwb, 131072);
  cvt_bf16_kernel<<<8192, 256, 0, stream>>>(data, datab, 8192 * 256);
  edge_pack_kernel<<<2048, 256, 0, stream>>>(edge, ep);
  for (int it = 0; it < 2; it++) {
    transpose_kernel<<<256, 256, 0, stream>>>(sq_w + it * 65536, sqT + it * 65536, 256, 256);
    transpose_kernel<<<256, 256, 0, stream>>>(so_w + it * 65536, soT + it * 65536, 256, 256);
  }

  for (int it = 0; it < 2; it++) {
    rarf_kernel<<<NHEAD * BB, 256, 0, stream>>>(relay, a1, a2, fcw_g, fcb_g, bqf,
                                                ra1, ra2, rf);
    lnei_kernel<<<2048, 256, 0, stream>>>(nodes, data, ng + it * 256, nb + it * 256,
                                          w1, w2, a1, a2, c1, c2, ra1, ra2,
                                          xnb, ei, ej);
    // GT = [xn;data] @ Bcat  (pre-projected per-head GAT values)
    g_gemm_kernel<<<dim3(4, 64), 256, 0, stream>>>(xnb, datab, Bcat, GT);
    gat_agg_kernel<<<NHEAD * BB * 16, 256, 0, stream>>>(GT, ei, ej, ep, rf, tmpb);
    // nodes = mask ? nodes + lrelu(temp @ fc_w + fc_b) : 0
    mfma_gemm_kernel<<<dim3(4, 64), 256, 0, stream>>>(tmpb, fcwT, fc_b, 8192, 1,
                                                      nodes, nodes, mask);
    build_y_kernel<<<BB * LP1, 256, 0, stream>>>(relay, nodes, yb);
    // kt = y @ sk_wT + sk_b
    mfma_gemm_kernel<<<dim3(4, 65), 256, 0, stream>>>(yb, skwb + it * 65536,
                                                      sk_b + it * 256, 8208, 2,
                                                      kt, nullptr, nullptr);
    small_gemm_kernel<<<BB, 256, 0, stream>>>(relay, sqT + it * 65536, sq_b + it * 256,
                                              qst, 0);
    star_attn_kernel<<<BB * NHEAD, 256, 0, stream>>>(qst, kt, mask, atts);
    small_gemm_kernel<<<BB, 256, 0, stream>>>(atts, soT + it * 65536, so_b + it * 256,
                                              relay, 1);
  }
}